// Round 5
// baseline (559.910 us; speedup 1.0000x reference)
//
#include <hip/hip_runtime.h>
#include <stdint.h>

#define N_NODES 20000
#define E_EDGES 320000
#define H_DIM 128
#define A_DIM 512
#define NEMB_N 400
#define K_SEL 80000u
#define NB1 16384
#define NB2 16384
#define CAND_MAX 8192
#define LO_F (-128.0f)
#define SCALE1 (16384.0f / 160.0f)   /* bins over [-128, 32) */

struct SelState {
    int b1; unsigned cum1; unsigned r1;
    int b2; unsigned cum2; unsigned r2;
    unsigned long long T;
};

// ---------------- threefry2x32 (JAX, 20 rounds) ----------------
__device__ __forceinline__ uint32_t rotl32(uint32_t x, int r) {
    return (x << r) | (x >> (32 - r));
}

__device__ __forceinline__ void threefry2x32(uint32_t k0, uint32_t k1,
                                             uint32_t& x0, uint32_t& x1) {
    uint32_t ks0 = k0, ks1 = k1, ks2 = k0 ^ k1 ^ 0x1BD11BDAu;
    x0 += ks0; x1 += ks1;
    x0 += x1; x1 = rotl32(x1, 13); x1 ^= x0;
    x0 += x1; x1 = rotl32(x1, 15); x1 ^= x0;
    x0 += x1; x1 = rotl32(x1, 26); x1 ^= x0;
    x0 += x1; x1 = rotl32(x1, 6);  x1 ^= x0;
    x0 += ks1; x1 += ks2 + 1u;
    x0 += x1; x1 = rotl32(x1, 17); x1 ^= x0;
    x0 += x1; x1 = rotl32(x1, 29); x1 ^= x0;
    x0 += x1; x1 = rotl32(x1, 16); x1 ^= x0;
    x0 += x1; x1 = rotl32(x1, 24); x1 ^= x0;
    x0 += ks2; x1 += ks0 + 2u;
    x0 += x1; x1 = rotl32(x1, 13); x1 ^= x0;
    x0 += x1; x1 = rotl32(x1, 15); x1 ^= x0;
    x0 += x1; x1 = rotl32(x1, 26); x1 ^= x0;
    x0 += x1; x1 = rotl32(x1, 6);  x1 ^= x0;
    x0 += ks0; x1 += ks1 + 3u;
    x0 += x1; x1 = rotl32(x1, 17); x1 ^= x0;
    x0 += x1; x1 = rotl32(x1, 29); x1 ^= x0;
    x0 += x1; x1 = rotl32(x1, 16); x1 ^= x0;
    x0 += x1; x1 = rotl32(x1, 24); x1 ^= x0;
    x0 += ks1; x1 += ks2 + 4u;
    x0 += x1; x1 = rotl32(x1, 13); x1 ^= x0;
    x0 += x1; x1 = rotl32(x1, 15); x1 ^= x0;
    x0 += x1; x1 = rotl32(x1, 26); x1 ^= x0;
    x0 += x1; x1 = rotl32(x1, 6);  x1 ^= x0;
    x0 += ks2; x1 += ks0 + 5u;
}

// JAX partitionable threefry: counter=(0,e), key=(0,42), bits = out0 ^ out1
__global__ __launch_bounds__(256) void k_rand(float* __restrict__ u) {
    int e = blockIdx.x * 256 + threadIdx.x;
    if (e >= E_EDGES) return;
    uint32_t x0 = 0u, x1 = (uint32_t)e;
    threefry2x32(0u, 42u, x0, x1);
    uint32_t bits = x0 ^ x1;
    uint32_t fb = (bits >> 9) | 0x3f800000u;
    u[e] = __uint_as_float(fb) - 1.0f;
}

// ---------- fused node precompute (f32): xl, v_node, q_node ----------
__global__ __launch_bounds__(128) void k_node(
    const float* __restrict__ x, const float* __restrict__ aerial,
    const float* __restrict__ Wlin, const float* __restrict__ blin,
    const float* __restrict__ Wq, const float* __restrict__ bq,
    const float* __restrict__ Wv, const float* __restrict__ bv,
    float* __restrict__ xl32, float* __restrict__ q32, float* __restrict__ v32) {
    __shared__ float xinT[H_DIM][8];   // [k][m]
    __shared__ float xsT[H_DIM][8];
    __shared__ float aerT[A_DIM][8];
    const int j = threadIdx.x;
    const int n0 = blockIdx.x * 8;
#pragma unroll
    for (int m = 0; m < 8; ++m) xinT[j][m] = x[(size_t)(n0 + m) * H_DIM + j];
#pragma unroll
    for (int m = 0; m < 8; ++m)
#pragma unroll
        for (int c = 0; c < 4; ++c)
            aerT[c * H_DIM + j][m] = aerial[(size_t)(n0 + m) * A_DIM + c * H_DIM + j];
    __syncthreads();
    // xl = x @ Wlin + blin
    float acc[8];
    {
        float bj = blin[j];
#pragma unroll
        for (int m = 0; m < 8; ++m) acc[m] = bj;
        for (int k = 0; k < H_DIM; ++k) {
            float w = Wlin[k * H_DIM + j];
            const float4* xp = (const float4*)&xinT[k][0];
            float4 a0 = xp[0], a1 = xp[1];
            acc[0] = fmaf(a0.x, w, acc[0]); acc[1] = fmaf(a0.y, w, acc[1]);
            acc[2] = fmaf(a0.z, w, acc[2]); acc[3] = fmaf(a0.w, w, acc[3]);
            acc[4] = fmaf(a1.x, w, acc[4]); acc[5] = fmaf(a1.y, w, acc[5]);
            acc[6] = fmaf(a1.z, w, acc[6]); acc[7] = fmaf(a1.w, w, acc[7]);
        }
    }
#pragma unroll
    for (int m = 0; m < 8; ++m) {
        xsT[j][m] = acc[m];
        xl32[(size_t)(n0 + m) * H_DIM + j] = acc[m];
    }
    __syncthreads();
    // v_node = xl @ Wv + bv
    {
        float bj = bv[j];
        float av[8];
#pragma unroll
        for (int m = 0; m < 8; ++m) av[m] = bj;
        for (int k = 0; k < H_DIM; ++k) {
            float w = Wv[k * H_DIM + j];
            const float4* xp = (const float4*)&xsT[k][0];
            float4 a0 = xp[0], a1 = xp[1];
            av[0] = fmaf(a0.x, w, av[0]); av[1] = fmaf(a0.y, w, av[1]);
            av[2] = fmaf(a0.z, w, av[2]); av[3] = fmaf(a0.w, w, av[3]);
            av[4] = fmaf(a1.x, w, av[4]); av[5] = fmaf(a1.y, w, av[5]);
            av[6] = fmaf(a1.z, w, av[6]); av[7] = fmaf(a1.w, w, av[7]);
        }
#pragma unroll
        for (int m = 0; m < 8; ++m) v32[(size_t)(n0 + m) * H_DIM + j] = av[m];
    }
    // q_node = xl @ Wq[0:128] + aerial @ Wq[128:640] + bq
    {
        float bj = bq[j];
        float aq[8];
#pragma unroll
        for (int m = 0; m < 8; ++m) aq[m] = bj;
        for (int k = 0; k < H_DIM; ++k) {
            float w = Wq[k * H_DIM + j];
            const float4* xp = (const float4*)&xsT[k][0];
            float4 a0 = xp[0], a1 = xp[1];
            aq[0] = fmaf(a0.x, w, aq[0]); aq[1] = fmaf(a0.y, w, aq[1]);
            aq[2] = fmaf(a0.z, w, aq[2]); aq[3] = fmaf(a0.w, w, aq[3]);
            aq[4] = fmaf(a1.x, w, aq[4]); aq[5] = fmaf(a1.y, w, aq[5]);
            aq[6] = fmaf(a1.z, w, aq[6]); aq[7] = fmaf(a1.w, w, aq[7]);
        }
        for (int k = 0; k < A_DIM; ++k) {
            float w = Wq[(size_t)(H_DIM + k) * H_DIM + j];
            const float4* xp = (const float4*)&aerT[k][0];
            float4 a0 = xp[0], a1 = xp[1];
            aq[0] = fmaf(a0.x, w, aq[0]); aq[1] = fmaf(a0.y, w, aq[1]);
            aq[2] = fmaf(a0.z, w, aq[2]); aq[3] = fmaf(a0.w, w, aq[3]);
            aq[4] = fmaf(a1.x, w, aq[4]); aq[5] = fmaf(a1.y, w, aq[5]);
            aq[6] = fmaf(a1.z, w, aq[6]); aq[7] = fmaf(a1.w, w, aq[7]);
        }
#pragma unroll
        for (int m = 0; m < 8; ++m) q32[(size_t)(n0 + m) * H_DIM + j] = aq[m];
    }
}

// dist_q = dist_table @ Wq[640:768]   (no bias; bq folded into q_node)
__global__ __launch_bounds__(128) void k_dist(
    const float* __restrict__ dtab, const float* __restrict__ Wq,
    float* __restrict__ dq32) {
    __shared__ float dsT[H_DIM][8];
    const int j = threadIdx.x;
    const int n0 = blockIdx.x * 8;
#pragma unroll
    for (int m = 0; m < 8; ++m) dsT[j][m] = dtab[(size_t)(n0 + m) * H_DIM + j];
    __syncthreads();
    float acc[8];
#pragma unroll
    for (int m = 0; m < 8; ++m) acc[m] = 0.0f;
    for (int k = 0; k < H_DIM; ++k) {
        float w = Wq[(size_t)(H_DIM + A_DIM + k) * H_DIM + j];
        const float4* xp = (const float4*)&dsT[k][0];
        float4 a0 = xp[0], a1 = xp[1];
        acc[0] = fmaf(a0.x, w, acc[0]); acc[1] = fmaf(a0.y, w, acc[1]);
        acc[2] = fmaf(a0.z, w, acc[2]); acc[3] = fmaf(a0.w, w, acc[3]);
        acc[4] = fmaf(a1.x, w, acc[4]); acc[5] = fmaf(a1.y, w, acc[5]);
        acc[6] = fmaf(a1.z, w, acc[6]); acc[7] = fmaf(a1.w, w, acc[7]);
    }
#pragma unroll
    for (int m = 0; m < 8; ++m) dq32[(size_t)(n0 + m) * H_DIM + j] = acc[m];
}

__device__ __forceinline__ int bin1_of(float s) {
    float t = (s - LO_F) * SCALE1;
    int b = (int)t;
    return min(max(b, 0), NB1 - 1);
}
__device__ __forceinline__ int bin2_of(float s, int b1) {
    float t = (s - LO_F) * SCALE1;
    float frac = t - (float)b1;
    int b = (int)(frac * (float)NB2);
    return min(max(b, 0), NB2 - 1);
}

// ---------- per-edge score: ONE edge per wave64, float2 per lane ----------
// Each row load is a single contiguous 512B segment across the wave
// (base + lane*8) -> VMEM coalescing fast path (2-rows-per-instruction
// variants cost ~130 cyc/instr regardless of locality/ILP: rounds 1-3).
// Reduction reproduces the original 32-partial tree bit-exactly:
//   even lane (x,y), odd lane (z,w); odd computes fmaf(z,z,w*w) == the
//   original inner chain; even completes fmaf(x,x,fmaf(y,y,T_odd)).
//   Butterfly offsets 32,16,8,4,2 pair even lanes exactly as 16,8,4,2,1
//   paired the 32 float4 partials (parity preserved; odd-lane values
//   never reach the even subtree). Lane-0 tail math unchanged.
__global__ __launch_bounds__(256) void k_score(
    const int* __restrict__ ei, const int* __restrict__ dist,
    const float* __restrict__ q32, const float* __restrict__ v32,
    const float* __restrict__ dq32, const float* __restrict__ u,
    unsigned long long* __restrict__ keys, float* __restrict__ s32o,
    unsigned* __restrict__ hist1) {
    const int wid = threadIdx.x >> 6, lane = threadIdx.x & 63;
    const int e = blockIdx.x * 4 + wid;
    const int s = ei[e], t = ei[E_EDGES + e];
    const int db = dist[e] / 50;
    const float2 q = ((const float2*)(q32 + (size_t)s * H_DIM))[lane];
    const float2 v = ((const float2*)(v32 + (size_t)t * H_DIM))[lane];
    const float2 d = ((const float2*)(dq32 + (size_t)db * H_DIM))[lane];
    float a0 = q.x + d.x - v.x;
    float a1 = q.y + d.y - v.y;
    float th = fmaf(a0, a0, a1 * a1);      // odd lane: fmaf(dz,dz,dw*dw)
    float tn = __shfl_xor(th, 1, 64);      // even lane receives T_odd
    float ss = fmaf(a0, a0, fmaf(a1, a1, tn));  // even: exact original chain
#pragma unroll
    for (int o = 32; o >= 2; o >>= 1) ss += __shfl_xor(ss, o, 64);
    if (lane == 0) {
        float nrm = sqrtf(ss);
        float uu = u[e];
        float a = -logf(uu + 1e-20f);
        float g = -logf(a + 1e-20f);
        float score = g - nrm;
        int ib = __float_as_int(score);
        unsigned m32 = (ib < 0) ? ~(unsigned)ib : ((unsigned)ib | 0x80000000u);
        // unique key: score-ordered high bits, lower edge index wins ties
        keys[e] = ((unsigned long long)m32 << 32) | (unsigned)(0xFFFFFFFFu - (unsigned)e);
        s32o[e] = score;
        atomicAdd(&hist1[bin1_of(score)], 1u);
    }
}

__global__ __launch_bounds__(256) void k_hist2(const float* __restrict__ s32,
                                               const SelState* __restrict__ st,
                                               unsigned* __restrict__ hist2) {
    int e = blockIdx.x * 256 + threadIdx.x;
    if (e >= E_EDGES) return;
    float s = s32[e];
    int b1 = bin1_of(s);
    if (b1 != st->b1) return;
    atomicAdd(&hist2[bin2_of(s, b1)], 1u);
}

// descending scan over 16384 bins to locate the bin holding the target rank
__global__ __launch_bounds__(256) void k_scan(const unsigned* __restrict__ hist,
                                              SelState* st, int phase) {
    __shared__ unsigned csum[256];
    __shared__ unsigned bins[64];
    __shared__ int selc;
    __shared__ unsigned cumbase;
    const int t = threadIdx.x;
    const unsigned target = (phase == 1) ? K_SEL : st->r1;
    unsigned s = 0;
    for (int i = 0; i < 64; ++i) s += hist[t * 64 + i];
    csum[t] = s;
    __syncthreads();
    if (t == 0) {
        unsigned cum = 0; int c = 255;
        for (; c >= 0; --c) {
            if (cum + csum[c] >= target) break;
            cum += csum[c];
        }
        selc = c; cumbase = cum;
    }
    __syncthreads();
    if (t < 64) bins[t] = hist[selc * 64 + t];
    __syncthreads();
    if (t == 0) {
        unsigned cum = cumbase; int b = -1;
        for (int i = 63; i >= 0; --i) {
            if (cum + bins[i] >= target) { b = selc * 64 + i; break; }
            cum += bins[i];
        }
        unsigned r = target - cum;
        if (phase == 1) { st->b1 = b; st->cum1 = cum; st->r1 = r; }
        else           { st->b2 = b; st->cum2 = cum; st->r2 = r; }
    }
}

__global__ __launch_bounds__(256) void k_collect(
    const float* __restrict__ s32, const unsigned long long* __restrict__ keys,
    const SelState* __restrict__ st, unsigned long long* __restrict__ cand,
    unsigned* __restrict__ cnt) {
    int e = blockIdx.x * 256 + threadIdx.x;
    if (e >= E_EDGES) return;
    float s = s32[e];
    int b1 = bin1_of(s);
    if (b1 != st->b1) return;
    if (bin2_of(s, b1) != st->b2) return;
    unsigned p = atomicAdd(cnt, 1u);
    if (p < CAND_MAX) cand[p] = keys[e];
}

// T = r2-th largest key among candidates (keys are unique)
__global__ __launch_bounds__(256) void k_thresh(
    const unsigned long long* __restrict__ cand, const unsigned* __restrict__ cnt,
    SelState* st) {
    int c = (int)min(*cnt, (unsigned)CAND_MAX);
    unsigned r2 = st->r2;
    for (int i = threadIdx.x; i < c; i += blockDim.x) {
        unsigned long long ki = cand[i];
        unsigned g = 0;
        for (int j = 0; j < c; ++j) g += (cand[j] > ki);
        if (g == r2 - 1) st->T = ki;
    }
}

// wave per edge: key >= T selects; scatter xl[src] into msg[tgt] + deg
__global__ __launch_bounds__(256) void k_scatter(
    const int* __restrict__ ei, const unsigned long long* __restrict__ keys,
    const SelState* __restrict__ st, const float* __restrict__ xl32,
    float* __restrict__ msg, float* __restrict__ deg) {
    const int wid = threadIdx.x >> 6, lane = threadIdx.x & 63;
    const int e = blockIdx.x * 4 + wid;
    if (keys[e] >= st->T) {
        int sidx = ei[e], tidx = ei[E_EDGES + e];
        const float* xp = xl32 + (size_t)sidx * H_DIM;
        float* mp = msg + (size_t)tidx * H_DIM;
        const int h = lane * 2;
        atomicAdd(&mp[h], xp[h]);
        atomicAdd(&mp[h + 1], xp[h + 1]);
        if (lane == 0) atomicAdd(&deg[tidx], 1.0f);
    }
}

// out = (msg/max(deg,1)) @ Wl + bl + xl @ Wr
__global__ __launch_bounds__(128) void k_out(
    const float* __restrict__ msg, const float* __restrict__ deg,
    const float* __restrict__ xl32, const float* __restrict__ Wl,
    const float* __restrict__ bl, const float* __restrict__ Wr,
    float* __restrict__ out) {
    __shared__ float axT[H_DIM][8];
    __shared__ float xxT[H_DIM][8];
    const int j = threadIdx.x;
    const int n0 = blockIdx.x * 8;
#pragma unroll
    for (int m = 0; m < 8; ++m) {
        float d = fmaxf(deg[n0 + m], 1.0f);
        axT[j][m] = msg[(size_t)(n0 + m) * H_DIM + j] / d;
        xxT[j][m] = xl32[(size_t)(n0 + m) * H_DIM + j];
    }
    __syncthreads();
    float acc[8];
    float bj = bl[j];
#pragma unroll
    for (int m = 0; m < 8; ++m) acc[m] = bj;
    for (int k = 0; k < H_DIM; ++k) {
        float wl = Wl[k * H_DIM + j];
        float wr = Wr[k * H_DIM + j];
        const float4* ap = (const float4*)&axT[k][0];
        const float4* xp = (const float4*)&xxT[k][0];
        float4 a0 = ap[0], a1 = ap[1];
        float4 x0 = xp[0], x1 = xp[1];
        acc[0] = fmaf(a0.x, wl, fmaf(x0.x, wr, acc[0]));
        acc[1] = fmaf(a0.y, wl, fmaf(x0.y, wr, acc[1]));
        acc[2] = fmaf(a0.z, wl, fmaf(x0.z, wr, acc[2]));
        acc[3] = fmaf(a0.w, wl, fmaf(x0.w, wr, acc[3]));
        acc[4] = fmaf(a1.x, wl, fmaf(x1.x, wr, acc[4]));
        acc[5] = fmaf(a1.y, wl, fmaf(x1.y, wr, acc[5]));
        acc[6] = fmaf(a1.z, wl, fmaf(x1.z, wr, acc[6]));
        acc[7] = fmaf(a1.w, wl, fmaf(x1.w, wr, acc[7]));
    }
#pragma unroll
    for (int m = 0; m < 8; ++m) out[(size_t)(n0 + m) * H_DIM + j] = acc[m];
}

extern "C" void kernel_launch(void* const* d_in, const int* in_sizes, int n_in,
                              void* d_out, int out_size, void* d_ws, size_t ws_size,
                              hipStream_t stream) {
    const float* x      = (const float*)d_in[0];
    const int*   ei     = (const int*)d_in[1];
    const int*   dist   = (const int*)d_in[2];
    const float* aerial = (const float*)d_in[3];
    const float* Wlin   = (const float*)d_in[4];
    const float* blin   = (const float*)d_in[5];
    const float* Wq     = (const float*)d_in[6];
    const float* bq     = (const float*)d_in[7];
    const float* Wv     = (const float*)d_in[8];
    const float* bv     = (const float*)d_in[9];
    const float* dtab   = (const float*)d_in[10];
    const float* Wl     = (const float*)d_in[11];
    const float* bl     = (const float*)d_in[12];
    const float* Wr     = (const float*)d_in[13];
    float* out = (float*)d_out;

    char* ws = (char*)d_ws;
    size_t off = 0;
    auto alloc = [&](size_t bytes) -> void* {
        void* p = ws + off;
        off += (bytes + 255) & ~(size_t)255;
        return p;
    };
    float* q32  = (float*)alloc((size_t)N_NODES * H_DIM * 4);
    float* v32  = (float*)alloc((size_t)N_NODES * H_DIM * 4);
    float* dq32 = (float*)alloc((size_t)NEMB_N * H_DIM * 4);
    unsigned long long* keys = (unsigned long long*)alloc((size_t)E_EDGES * 8);
    float* xl32 = (float*)alloc((size_t)N_NODES * H_DIM * 4);
    float* urnd = (float*)alloc((size_t)E_EDGES * 4);
    float* s32  = (float*)alloc((size_t)E_EDGES * 4);
    char* zbase = ws + off;
    float* msg  = (float*)alloc((size_t)N_NODES * H_DIM * 4);
    float* deg  = (float*)alloc((size_t)N_NODES * 4);
    unsigned* hist1 = (unsigned*)alloc((size_t)NB1 * 4);
    unsigned* hist2 = (unsigned*)alloc((size_t)NB2 * 4);
    unsigned long long* cand = (unsigned long long*)alloc((size_t)CAND_MAX * 8);
    unsigned* counters = (unsigned*)alloc(256);   // [0]=candCount
    SelState* st = (SelState*)alloc(256);
    size_t zlen = (size_t)((ws + off) - zbase);

    hipMemsetAsync(zbase, 0, zlen, stream);

    k_node<<<N_NODES / 8, 128, 0, stream>>>(x, aerial, Wlin, blin, Wq, bq, Wv, bv,
                                            xl32, q32, v32);
    k_dist<<<NEMB_N / 8, 128, 0, stream>>>(dtab, Wq, dq32);
    k_rand<<<(E_EDGES + 255) / 256, 256, 0, stream>>>(urnd);
    k_score<<<E_EDGES / 4, 256, 0, stream>>>(ei, dist, q32, v32, dq32, urnd, keys, s32, hist1);
    k_scan<<<1, 256, 0, stream>>>(hist1, st, 1);
    k_hist2<<<(E_EDGES + 255) / 256, 256, 0, stream>>>(s32, st, hist2);
    k_scan<<<1, 256, 0, stream>>>(hist2, st, 2);
    k_collect<<<(E_EDGES + 255) / 256, 256, 0, stream>>>(s32, keys, st, cand, &counters[0]);
    k_thresh<<<1, 256, 0, stream>>>(cand, &counters[0], st);
    k_scatter<<<E_EDGES / 4, 256, 0, stream>>>(ei, keys, st, xl32, msg, deg);
    k_out<<<N_NODES / 8, 128, 0, stream>>>(msg, deg, xl32, Wl, bl, Wr, out);
}

// Round 6
// 553.418 us; speedup vs baseline: 1.0117x; 1.0117x over previous
//
#include <hip/hip_runtime.h>
#include <stdint.h>

#define N_NODES 20000
#define E_EDGES 320000
#define H_DIM 128
#define A_DIM 512
#define NEMB_N 400
#define K_SEL 80000u
#define NB1 16384
#define NB2 16384
#define CAND_MAX 8192
#define LO_F (-128.0f)
#define SCALE1 (16384.0f / 160.0f)   /* bins over [-128, 32) */

struct SelState {
    int b1; unsigned cum1; unsigned r1;
    int b2; unsigned cum2; unsigned r2;
    unsigned long long T;
};

// ---------------- threefry2x32 (JAX, 20 rounds) ----------------
__device__ __forceinline__ uint32_t rotl32(uint32_t x, int r) {
    return (x << r) | (x >> (32 - r));
}

__device__ __forceinline__ void threefry2x32(uint32_t k0, uint32_t k1,
                                             uint32_t& x0, uint32_t& x1) {
    uint32_t ks0 = k0, ks1 = k1, ks2 = k0 ^ k1 ^ 0x1BD11BDAu;
    x0 += ks0; x1 += ks1;
    x0 += x1; x1 = rotl32(x1, 13); x1 ^= x0;
    x0 += x1; x1 = rotl32(x1, 15); x1 ^= x0;
    x0 += x1; x1 = rotl32(x1, 26); x1 ^= x0;
    x0 += x1; x1 = rotl32(x1, 6);  x1 ^= x0;
    x0 += ks1; x1 += ks2 + 1u;
    x0 += x1; x1 = rotl32(x1, 17); x1 ^= x0;
    x0 += x1; x1 = rotl32(x1, 29); x1 ^= x0;
    x0 += x1; x1 = rotl32(x1, 16); x1 ^= x0;
    x0 += x1; x1 = rotl32(x1, 24); x1 ^= x0;
    x0 += ks2; x1 += ks0 + 2u;
    x0 += x1; x1 = rotl32(x1, 13); x1 ^= x0;
    x0 += x1; x1 = rotl32(x1, 15); x1 ^= x0;
    x0 += x1; x1 = rotl32(x1, 26); x1 ^= x0;
    x0 += x1; x1 = rotl32(x1, 6);  x1 ^= x0;
    x0 += ks0; x1 += ks1 + 3u;
    x0 += x1; x1 = rotl32(x1, 17); x1 ^= x0;
    x0 += x1; x1 = rotl32(x1, 29); x1 ^= x0;
    x0 += x1; x1 = rotl32(x1, 16); x1 ^= x0;
    x0 += x1; x1 = rotl32(x1, 24); x1 ^= x0;
    x0 += ks1; x1 += ks2 + 4u;
    x0 += x1; x1 = rotl32(x1, 13); x1 ^= x0;
    x0 += x1; x1 = rotl32(x1, 15); x1 ^= x0;
    x0 += x1; x1 = rotl32(x1, 26); x1 ^= x0;
    x0 += x1; x1 = rotl32(x1, 6);  x1 ^= x0;
    x0 += ks2; x1 += ks0 + 5u;
}

// JAX partitionable threefry: counter=(0,e), key=(0,42), bits = out0 ^ out1
__global__ __launch_bounds__(256) void k_rand(float* __restrict__ u) {
    int e = blockIdx.x * 256 + threadIdx.x;
    if (e >= E_EDGES) return;
    uint32_t x0 = 0u, x1 = (uint32_t)e;
    threefry2x32(0u, 42u, x0, x1);
    uint32_t bits = x0 ^ x1;
    uint32_t fb = (bits >> 9) | 0x3f800000u;
    u[e] = __uint_as_float(fb) - 1.0f;
}

// ---------- fused node precompute (f32): xl, v_node, q_node ----------
// 16 nodes per block, 256 threads: thread (j = tid&127, h = tid>>7) owns
// output column j for nodes h*8..h*8+7. Halves per-node weight streaming
// vs the 8-node tile. Per-output k-loop order identical -> bit-exact.
__global__ __launch_bounds__(256) void k_node(
    const float* __restrict__ x, const float* __restrict__ aerial,
    const float* __restrict__ Wlin, const float* __restrict__ blin,
    const float* __restrict__ Wq, const float* __restrict__ bq,
    const float* __restrict__ Wv, const float* __restrict__ bv,
    float* __restrict__ xl32, float* __restrict__ q32, float* __restrict__ v32) {
    __shared__ float xinT[H_DIM][16];   // [k][m]
    __shared__ float xsT[H_DIM][16];
    __shared__ float aerT[A_DIM][16];
    const int j = threadIdx.x & 127;
    const int h = threadIdx.x >> 7;     // 0 or 1
    const int mb = h * 8;
    const int n0 = blockIdx.x * 16;
#pragma unroll
    for (int m = 0; m < 8; ++m)
        xinT[j][mb + m] = x[(size_t)(n0 + mb + m) * H_DIM + j];
#pragma unroll
    for (int m = 0; m < 8; ++m)
#pragma unroll
        for (int c = 0; c < 4; ++c)
            aerT[c * H_DIM + j][mb + m] =
                aerial[(size_t)(n0 + mb + m) * A_DIM + c * H_DIM + j];
    __syncthreads();
    // xl = x @ Wlin + blin
    float acc[8];
    {
        float bj = blin[j];
#pragma unroll
        for (int m = 0; m < 8; ++m) acc[m] = bj;
        for (int k = 0; k < H_DIM; ++k) {
            float w = Wlin[k * H_DIM + j];
            const float4* xp = (const float4*)&xinT[k][mb];
            float4 a0 = xp[0], a1 = xp[1];
            acc[0] = fmaf(a0.x, w, acc[0]); acc[1] = fmaf(a0.y, w, acc[1]);
            acc[2] = fmaf(a0.z, w, acc[2]); acc[3] = fmaf(a0.w, w, acc[3]);
            acc[4] = fmaf(a1.x, w, acc[4]); acc[5] = fmaf(a1.y, w, acc[5]);
            acc[6] = fmaf(a1.z, w, acc[6]); acc[7] = fmaf(a1.w, w, acc[7]);
        }
    }
#pragma unroll
    for (int m = 0; m < 8; ++m) {
        xsT[j][mb + m] = acc[m];
        xl32[(size_t)(n0 + mb + m) * H_DIM + j] = acc[m];
    }
    __syncthreads();
    // v_node = xl @ Wv + bv
    {
        float bj = bv[j];
        float av[8];
#pragma unroll
        for (int m = 0; m < 8; ++m) av[m] = bj;
        for (int k = 0; k < H_DIM; ++k) {
            float w = Wv[k * H_DIM + j];
            const float4* xp = (const float4*)&xsT[k][mb];
            float4 a0 = xp[0], a1 = xp[1];
            av[0] = fmaf(a0.x, w, av[0]); av[1] = fmaf(a0.y, w, av[1]);
            av[2] = fmaf(a0.z, w, av[2]); av[3] = fmaf(a0.w, w, av[3]);
            av[4] = fmaf(a1.x, w, av[4]); av[5] = fmaf(a1.y, w, av[5]);
            av[6] = fmaf(a1.z, w, av[6]); av[7] = fmaf(a1.w, w, av[7]);
        }
#pragma unroll
        for (int m = 0; m < 8; ++m)
            v32[(size_t)(n0 + mb + m) * H_DIM + j] = av[m];
    }
    // q_node = xl @ Wq[0:128] + aerial @ Wq[128:640] + bq
    {
        float bj = bq[j];
        float aq[8];
#pragma unroll
        for (int m = 0; m < 8; ++m) aq[m] = bj;
        for (int k = 0; k < H_DIM; ++k) {
            float w = Wq[k * H_DIM + j];
            const float4* xp = (const float4*)&xsT[k][mb];
            float4 a0 = xp[0], a1 = xp[1];
            aq[0] = fmaf(a0.x, w, aq[0]); aq[1] = fmaf(a0.y, w, aq[1]);
            aq[2] = fmaf(a0.z, w, aq[2]); aq[3] = fmaf(a0.w, w, aq[3]);
            aq[4] = fmaf(a1.x, w, aq[4]); aq[5] = fmaf(a1.y, w, aq[5]);
            aq[6] = fmaf(a1.z, w, aq[6]); aq[7] = fmaf(a1.w, w, aq[7]);
        }
        for (int k = 0; k < A_DIM; ++k) {
            float w = Wq[(size_t)(H_DIM + k) * H_DIM + j];
            const float4* xp = (const float4*)&aerT[k][mb];
            float4 a0 = xp[0], a1 = xp[1];
            aq[0] = fmaf(a0.x, w, aq[0]); aq[1] = fmaf(a0.y, w, aq[1]);
            aq[2] = fmaf(a0.z, w, aq[2]); aq[3] = fmaf(a0.w, w, aq[3]);
            aq[4] = fmaf(a1.x, w, aq[4]); aq[5] = fmaf(a1.y, w, aq[5]);
            aq[6] = fmaf(a1.z, w, aq[6]); aq[7] = fmaf(a1.w, w, aq[7]);
        }
#pragma unroll
        for (int m = 0; m < 8; ++m)
            q32[(size_t)(n0 + mb + m) * H_DIM + j] = aq[m];
    }
}

// dist_q = dist_table @ Wq[640:768]   (no bias; bq folded into q_node)
__global__ __launch_bounds__(128) void k_dist(
    const float* __restrict__ dtab, const float* __restrict__ Wq,
    float* __restrict__ dq32) {
    __shared__ float dsT[H_DIM][8];
    const int j = threadIdx.x;
    const int n0 = blockIdx.x * 8;
#pragma unroll
    for (int m = 0; m < 8; ++m) dsT[j][m] = dtab[(size_t)(n0 + m) * H_DIM + j];
    __syncthreads();
    float acc[8];
#pragma unroll
    for (int m = 0; m < 8; ++m) acc[m] = 0.0f;
    for (int k = 0; k < H_DIM; ++k) {
        float w = Wq[(size_t)(H_DIM + A_DIM + k) * H_DIM + j];
        const float4* xp = (const float4*)&dsT[k][0];
        float4 a0 = xp[0], a1 = xp[1];
        acc[0] = fmaf(a0.x, w, acc[0]); acc[1] = fmaf(a0.y, w, acc[1]);
        acc[2] = fmaf(a0.z, w, acc[2]); acc[3] = fmaf(a0.w, w, acc[3]);
        acc[4] = fmaf(a1.x, w, acc[4]); acc[5] = fmaf(a1.y, w, acc[5]);
        acc[6] = fmaf(a1.z, w, acc[6]); acc[7] = fmaf(a1.w, w, acc[7]);
    }
#pragma unroll
    for (int m = 0; m < 8; ++m) dq32[(size_t)(n0 + m) * H_DIM + j] = acc[m];
}

__device__ __forceinline__ int bin1_of(float s) {
    float t = (s - LO_F) * SCALE1;
    int b = (int)t;
    return min(max(b, 0), NB1 - 1);
}
__device__ __forceinline__ int bin2_of(float s, int b1) {
    float t = (s - LO_F) * SCALE1;
    float frac = t - (float)b1;
    int b = (int)(frac * (float)NB2);
    return min(max(b, 0), NB2 - 1);
}

// ---------- per-edge score: 32-lane group handles 4 edges (R3, fastest) ----------
// 12 independent float4 gathers in flight; butterfly reduces 4 sums
// simultaneously; tail runs on lanes 0-3 in parallel. Per-edge arithmetic
// bit-identical to the 1-edge-per-group original.
__global__ __launch_bounds__(256) void k_score(
    const int* __restrict__ ei, const int* __restrict__ dist,
    const float* __restrict__ q32, const float* __restrict__ v32,
    const float* __restrict__ dq32, const float* __restrict__ u,
    unsigned long long* __restrict__ keys, float* __restrict__ s32o,
    unsigned* __restrict__ hist1) {
    const int g = threadIdx.x >> 5, lane = threadIdx.x & 31;
    const int e0 = blockIdx.x * 32 + g * 4;

    const int s0 = ei[e0 + 0], s1 = ei[e0 + 1], s2 = ei[e0 + 2], s3 = ei[e0 + 3];
    const int t0 = ei[E_EDGES + e0 + 0], t1 = ei[E_EDGES + e0 + 1];
    const int t2 = ei[E_EDGES + e0 + 2], t3 = ei[E_EDGES + e0 + 3];
    const int d0 = dist[e0 + 0] / 50, d1 = dist[e0 + 1] / 50;
    const int d2 = dist[e0 + 2] / 50, d3 = dist[e0 + 3] / 50;

    float4 q0 = ((const float4*)(q32 + (size_t)s0 * H_DIM))[lane];
    float4 q1 = ((const float4*)(q32 + (size_t)s1 * H_DIM))[lane];
    float4 q2 = ((const float4*)(q32 + (size_t)s2 * H_DIM))[lane];
    float4 q3 = ((const float4*)(q32 + (size_t)s3 * H_DIM))[lane];
    float4 v0 = ((const float4*)(v32 + (size_t)t0 * H_DIM))[lane];
    float4 v1 = ((const float4*)(v32 + (size_t)t1 * H_DIM))[lane];
    float4 v2 = ((const float4*)(v32 + (size_t)t2 * H_DIM))[lane];
    float4 v3 = ((const float4*)(v32 + (size_t)t3 * H_DIM))[lane];
    float4 w0 = ((const float4*)(dq32 + (size_t)d0 * H_DIM))[lane];
    float4 w1 = ((const float4*)(dq32 + (size_t)d1 * H_DIM))[lane];
    float4 w2 = ((const float4*)(dq32 + (size_t)d2 * H_DIM))[lane];
    float4 w3 = ((const float4*)(dq32 + (size_t)d3 * H_DIM))[lane];

    float ax, ay, az, aw;
    ax = q0.x + w0.x - v0.x; ay = q0.y + w0.y - v0.y;
    az = q0.z + w0.z - v0.z; aw = q0.w + w0.w - v0.w;
    float ss0 = fmaf(ax, ax, fmaf(ay, ay, fmaf(az, az, aw * aw)));
    ax = q1.x + w1.x - v1.x; ay = q1.y + w1.y - v1.y;
    az = q1.z + w1.z - v1.z; aw = q1.w + w1.w - v1.w;
    float ss1 = fmaf(ax, ax, fmaf(ay, ay, fmaf(az, az, aw * aw)));
    ax = q2.x + w2.x - v2.x; ay = q2.y + w2.y - v2.y;
    az = q2.z + w2.z - v2.z; aw = q2.w + w2.w - v2.w;
    float ss2 = fmaf(ax, ax, fmaf(ay, ay, fmaf(az, az, aw * aw)));
    ax = q3.x + w3.x - v3.x; ay = q3.y + w3.y - v3.y;
    az = q3.z + w3.z - v3.z; aw = q3.w + w3.w - v3.w;
    float ss3 = fmaf(ax, ax, fmaf(ay, ay, fmaf(az, az, aw * aw)));

#pragma unroll
    for (int o = 16; o > 0; o >>= 1) {
        ss0 += __shfl_xor(ss0, o, 64);
        ss1 += __shfl_xor(ss1, o, 64);
        ss2 += __shfl_xor(ss2, o, 64);
        ss3 += __shfl_xor(ss3, o, 64);
    }
    if (lane < 4) {
        float ssv = (lane == 0) ? ss0 : (lane == 1) ? ss1 : (lane == 2) ? ss2 : ss3;
        const int e = e0 + lane;
        float nrm = sqrtf(ssv);
        float uu = u[e];
        float a = -logf(uu + 1e-20f);
        float gm = -logf(a + 1e-20f);
        float score = gm - nrm;
        int ib = __float_as_int(score);
        unsigned m32 = (ib < 0) ? ~(unsigned)ib : ((unsigned)ib | 0x80000000u);
        // unique key: score-ordered high bits, lower edge index wins ties
        keys[e] = ((unsigned long long)m32 << 32) | (unsigned)(0xFFFFFFFFu - (unsigned)e);
        s32o[e] = score;
        atomicAdd(&hist1[bin1_of(score)], 1u);
    }
}

__global__ __launch_bounds__(256) void k_hist2(const float* __restrict__ s32,
                                               const SelState* __restrict__ st,
                                               unsigned* __restrict__ hist2) {
    int e = blockIdx.x * 256 + threadIdx.x;
    if (e >= E_EDGES) return;
    float s = s32[e];
    int b1 = bin1_of(s);
    if (b1 != st->b1) return;
    atomicAdd(&hist2[bin2_of(s, b1)], 1u);
}

// descending scan over 16384 bins to locate the bin holding the target rank
__global__ __launch_bounds__(256) void k_scan(const unsigned* __restrict__ hist,
                                              SelState* st, int phase) {
    __shared__ unsigned csum[256];
    __shared__ unsigned bins[64];
    __shared__ int selc;
    __shared__ unsigned cumbase;
    const int t = threadIdx.x;
    const unsigned target = (phase == 1) ? K_SEL : st->r1;
    unsigned s = 0;
    for (int i = 0; i < 64; ++i) s += hist[t * 64 + i];
    csum[t] = s;
    __syncthreads();
    if (t == 0) {
        unsigned cum = 0; int c = 255;
        for (; c >= 0; --c) {
            if (cum + csum[c] >= target) break;
            cum += csum[c];
        }
        selc = c; cumbase = cum;
    }
    __syncthreads();
    if (t < 64) bins[t] = hist[selc * 64 + t];
    __syncthreads();
    if (t == 0) {
        unsigned cum = cumbase; int b = -1;
        for (int i = 63; i >= 0; --i) {
            if (cum + bins[i] >= target) { b = selc * 64 + i; break; }
            cum += bins[i];
        }
        unsigned r = target - cum;
        if (phase == 1) { st->b1 = b; st->cum1 = cum; st->r1 = r; }
        else           { st->b2 = b; st->cum2 = cum; st->r2 = r; }
    }
}

__global__ __launch_bounds__(256) void k_collect(
    const float* __restrict__ s32, const unsigned long long* __restrict__ keys,
    const SelState* __restrict__ st, unsigned long long* __restrict__ cand,
    unsigned* __restrict__ cnt) {
    int e = blockIdx.x * 256 + threadIdx.x;
    if (e >= E_EDGES) return;
    float s = s32[e];
    int b1 = bin1_of(s);
    if (b1 != st->b1) return;
    if (bin2_of(s, b1) != st->b2) return;
    unsigned p = atomicAdd(cnt, 1u);
    if (p < CAND_MAX) cand[p] = keys[e];
}

// T = r2-th largest key among candidates (keys are unique)
__global__ __launch_bounds__(256) void k_thresh(
    const unsigned long long* __restrict__ cand, const unsigned* __restrict__ cnt,
    SelState* st) {
    int c = (int)min(*cnt, (unsigned)CAND_MAX);
    unsigned r2 = st->r2;
    for (int i = threadIdx.x; i < c; i += blockDim.x) {
        unsigned long long ki = cand[i];
        unsigned g = 0;
        for (int j = 0; j < c; ++j) g += (cand[j] > ki);
        if (g == r2 - 1) st->T = ki;
    }
}

// ---------- selected-edge aggregation: bucket by tgt, then reduce ----------
// Replaces the 10.24M-dword-atomic scatter with: count (80k atomics) ->
// prefix -> place (80k atomics) -> per-node register reduction (no atomics).
// Accumulation order was already atomic-nondeterministic before, and
// deg == (float)cnt exactly (repeated +1.0f is exact for cnt < 2^24).
__global__ __launch_bounds__(256) void k_selcnt(
    const int* __restrict__ ei, const unsigned long long* __restrict__ keys,
    const SelState* __restrict__ st, unsigned* __restrict__ cnt_tgt) {
    int e = blockIdx.x * 256 + threadIdx.x;
    if (e >= E_EDGES) return;
    if (keys[e] >= st->T) atomicAdd(&cnt_tgt[ei[E_EDGES + e]], 1u);
}

// exclusive prefix over N_NODES bins, single block; writes two copies
// (off_tgt stays pristine for k_aggr, off_work is consumed by k_selplace)
__global__ __launch_bounds__(256) void k_prefix(
    const unsigned* __restrict__ cnt, unsigned* __restrict__ off,
    unsigned* __restrict__ off2) {
    __shared__ unsigned ssum[256];
    const int t = threadIdx.x;
    const int PER = (N_NODES + 255) / 256;   // 79
    unsigned s = 0;
    for (int i = 0; i < PER; ++i) {
        int idx = t * PER + i;
        if (idx < N_NODES) s += cnt[idx];
    }
    ssum[t] = s;
    __syncthreads();
    if (t == 0) {
        unsigned acc = 0;
        for (int i = 0; i < 256; ++i) { unsigned v = ssum[i]; ssum[i] = acc; acc += v; }
    }
    __syncthreads();
    unsigned run = ssum[t];
    for (int i = 0; i < PER; ++i) {
        int idx = t * PER + i;
        if (idx < N_NODES) { off[idx] = run; off2[idx] = run; run += cnt[idx]; }
    }
}

__global__ __launch_bounds__(256) void k_selplace(
    const int* __restrict__ ei, const unsigned long long* __restrict__ keys,
    const SelState* __restrict__ st, unsigned* __restrict__ off_work,
    int* __restrict__ selsrc) {
    int e = blockIdx.x * 256 + threadIdx.x;
    if (e >= E_EDGES) return;
    if (keys[e] >= st->T) {
        unsigned p = atomicAdd(&off_work[ei[E_EDGES + e]], 1u);
        if (p < K_SEL) selsrc[p] = ei[e];
    }
}

// wave per node: sum xl rows of its selected in-edges in registers,
// write aggr = sum / max(cnt,1) directly (feeds k_out; no msg/deg arrays)
__global__ __launch_bounds__(256) void k_aggr(
    const unsigned* __restrict__ cnt_tgt, const unsigned* __restrict__ off_tgt,
    const int* __restrict__ selsrc, const float* __restrict__ xl32,
    float* __restrict__ aggr) {
    const int wid = threadIdx.x >> 6, lane = threadIdx.x & 63;
    const int n = blockIdx.x * 4 + wid;
    const int cnt = (int)cnt_tgt[n];
    const unsigned start = off_tgt[n];
    float ax = 0.0f, ay = 0.0f;
    for (int i = 0; i < cnt; ++i) {
        int s = selsrc[start + i];
        const float2 v = ((const float2*)(xl32 + (size_t)s * H_DIM))[lane];
        ax += v.x; ay += v.y;
    }
    float dm = fmaxf((float)cnt, 1.0f);
    float2 o; o.x = ax / dm; o.y = ay / dm;
    ((float2*)(aggr + (size_t)n * H_DIM))[lane] = o;
}

// out = aggr @ Wl + bl + xl @ Wr   (16 nodes/block, 256 threads)
__global__ __launch_bounds__(256) void k_out(
    const float* __restrict__ aggr, const float* __restrict__ xl32,
    const float* __restrict__ Wl, const float* __restrict__ bl,
    const float* __restrict__ Wr, float* __restrict__ out) {
    __shared__ float axT[H_DIM][16];
    __shared__ float xxT[H_DIM][16];
    const int j = threadIdx.x & 127;
    const int h = threadIdx.x >> 7;
    const int mb = h * 8;
    const int n0 = blockIdx.x * 16;
#pragma unroll
    for (int m = 0; m < 8; ++m) {
        axT[j][mb + m] = aggr[(size_t)(n0 + mb + m) * H_DIM + j];
        xxT[j][mb + m] = xl32[(size_t)(n0 + mb + m) * H_DIM + j];
    }
    __syncthreads();
    float acc[8];
    float bj = bl[j];
#pragma unroll
    for (int m = 0; m < 8; ++m) acc[m] = bj;
    for (int k = 0; k < H_DIM; ++k) {
        float wl = Wl[k * H_DIM + j];
        float wr = Wr[k * H_DIM + j];
        const float4* ap = (const float4*)&axT[k][mb];
        const float4* xp = (const float4*)&xxT[k][mb];
        float4 a0 = ap[0], a1 = ap[1];
        float4 x0 = xp[0], x1 = xp[1];
        acc[0] = fmaf(a0.x, wl, fmaf(x0.x, wr, acc[0]));
        acc[1] = fmaf(a0.y, wl, fmaf(x0.y, wr, acc[1]));
        acc[2] = fmaf(a0.z, wl, fmaf(x0.z, wr, acc[2]));
        acc[3] = fmaf(a0.w, wl, fmaf(x0.w, wr, acc[3]));
        acc[4] = fmaf(a1.x, wl, fmaf(x1.x, wr, acc[4]));
        acc[5] = fmaf(a1.y, wl, fmaf(x1.y, wr, acc[5]));
        acc[6] = fmaf(a1.z, wl, fmaf(x1.z, wr, acc[6]));
        acc[7] = fmaf(a1.w, wl, fmaf(x1.w, wr, acc[7]));
    }
#pragma unroll
    for (int m = 0; m < 8; ++m)
        out[(size_t)(n0 + mb + m) * H_DIM + j] = acc[m];
}

extern "C" void kernel_launch(void* const* d_in, const int* in_sizes, int n_in,
                              void* d_out, int out_size, void* d_ws, size_t ws_size,
                              hipStream_t stream) {
    const float* x      = (const float*)d_in[0];
    const int*   ei     = (const int*)d_in[1];
    const int*   dist   = (const int*)d_in[2];
    const float* aerial = (const float*)d_in[3];
    const float* Wlin   = (const float*)d_in[4];
    const float* blin   = (const float*)d_in[5];
    const float* Wq     = (const float*)d_in[6];
    const float* bq     = (const float*)d_in[7];
    const float* Wv     = (const float*)d_in[8];
    const float* bv     = (const float*)d_in[9];
    const float* dtab   = (const float*)d_in[10];
    const float* Wl     = (const float*)d_in[11];
    const float* bl     = (const float*)d_in[12];
    const float* Wr     = (const float*)d_in[13];
    float* out = (float*)d_out;

    char* ws = (char*)d_ws;
    size_t off = 0;
    auto alloc = [&](size_t bytes) -> void* {
        void* p = ws + off;
        off += (bytes + 255) & ~(size_t)255;
        return p;
    };
    float* q32  = (float*)alloc((size_t)N_NODES * H_DIM * 4);
    float* v32  = (float*)alloc((size_t)N_NODES * H_DIM * 4);
    float* dq32 = (float*)alloc((size_t)NEMB_N * H_DIM * 4);
    unsigned long long* keys = (unsigned long long*)alloc((size_t)E_EDGES * 8);
    float* xl32 = (float*)alloc((size_t)N_NODES * H_DIM * 4);
    float* urnd = (float*)alloc((size_t)E_EDGES * 4);
    float* s32  = (float*)alloc((size_t)E_EDGES * 4);
    float* aggr = (float*)alloc((size_t)N_NODES * H_DIM * 4);
    int* selsrc = (int*)alloc((size_t)K_SEL * 4);
    unsigned* off_tgt  = (unsigned*)alloc((size_t)N_NODES * 4);
    unsigned* off_work = (unsigned*)alloc((size_t)N_NODES * 4);
    unsigned long long* cand = (unsigned long long*)alloc((size_t)CAND_MAX * 8);
    char* zbase = ws + off;
    unsigned* cnt_tgt = (unsigned*)alloc((size_t)N_NODES * 4);
    unsigned* hist1 = (unsigned*)alloc((size_t)NB1 * 4);
    unsigned* hist2 = (unsigned*)alloc((size_t)NB2 * 4);
    unsigned* counters = (unsigned*)alloc(256);   // [0]=candCount
    SelState* st = (SelState*)alloc(256);
    size_t zlen = (size_t)((ws + off) - zbase);

    hipMemsetAsync(zbase, 0, zlen, stream);

    k_node<<<N_NODES / 16, 256, 0, stream>>>(x, aerial, Wlin, blin, Wq, bq, Wv, bv,
                                             xl32, q32, v32);
    k_dist<<<NEMB_N / 8, 128, 0, stream>>>(dtab, Wq, dq32);
    k_rand<<<(E_EDGES + 255) / 256, 256, 0, stream>>>(urnd);
    k_score<<<E_EDGES / 32, 256, 0, stream>>>(ei, dist, q32, v32, dq32, urnd,
                                              keys, s32, hist1);
    k_scan<<<1, 256, 0, stream>>>(hist1, st, 1);
    k_hist2<<<(E_EDGES + 255) / 256, 256, 0, stream>>>(s32, st, hist2);
    k_scan<<<1, 256, 0, stream>>>(hist2, st, 2);
    k_collect<<<(E_EDGES + 255) / 256, 256, 0, stream>>>(s32, keys, st, cand, &counters[0]);
    k_thresh<<<1, 256, 0, stream>>>(cand, &counters[0], st);
    k_selcnt<<<(E_EDGES + 255) / 256, 256, 0, stream>>>(ei, keys, st, cnt_tgt);
    k_prefix<<<1, 256, 0, stream>>>(cnt_tgt, off_tgt, off_work);
    k_selplace<<<(E_EDGES + 255) / 256, 256, 0, stream>>>(ei, keys, st, off_work, selsrc);
    k_aggr<<<N_NODES / 4, 256, 0, stream>>>(cnt_tgt, off_tgt, selsrc, xl32, aggr);
    k_out<<<N_NODES / 16, 256, 0, stream>>>(aggr, xl32, Wl, bl, Wr, out);
}

// Round 8
// 521.569 us; speedup vs baseline: 1.0735x; 1.0611x over previous
//
#include <hip/hip_runtime.h>
#include <stdint.h>

#define N_NODES 20000
#define E_EDGES 320000
#define H_DIM 128
#define A_DIM 512
#define NEMB_N 400
#define K_SEL 80000u
#define NB1 16384
#define NB2 16384
#define CAND_MAX 8192
#define LO_F (-128.0f)
#define SCALE1 (16384.0f / 160.0f)   /* bins over [-128, 32) */

#define NODE_BLKS (N_NODES / 8)      /* 2500 */
#define DIST_BLKS (NEMB_N / 8)       /* 50   */

struct SelState {
    int b1; unsigned cum1; unsigned r1;
    int b2; unsigned cum2; unsigned r2;
    unsigned long long T;
};

// ---------------- threefry2x32 (JAX, 20 rounds) ----------------
__device__ __forceinline__ uint32_t rotl32(uint32_t x, int r) {
    return (x << r) | (x >> (32 - r));
}

__device__ __forceinline__ void threefry2x32(uint32_t k0, uint32_t k1,
                                             uint32_t& x0, uint32_t& x1) {
    uint32_t ks0 = k0, ks1 = k1, ks2 = k0 ^ k1 ^ 0x1BD11BDAu;
    x0 += ks0; x1 += ks1;
    x0 += x1; x1 = rotl32(x1, 13); x1 ^= x0;
    x0 += x1; x1 = rotl32(x1, 15); x1 ^= x0;
    x0 += x1; x1 = rotl32(x1, 26); x1 ^= x0;
    x0 += x1; x1 = rotl32(x1, 6);  x1 ^= x0;
    x0 += ks1; x1 += ks2 + 1u;
    x0 += x1; x1 = rotl32(x1, 17); x1 ^= x0;
    x0 += x1; x1 = rotl32(x1, 29); x1 ^= x0;
    x0 += x1; x1 = rotl32(x1, 16); x1 ^= x0;
    x0 += x1; x1 = rotl32(x1, 24); x1 ^= x0;
    x0 += ks2; x1 += ks0 + 2u;
    x0 += x1; x1 = rotl32(x1, 13); x1 ^= x0;
    x0 += x1; x1 = rotl32(x1, 15); x1 ^= x0;
    x0 += x1; x1 = rotl32(x1, 26); x1 ^= x0;
    x0 += x1; x1 = rotl32(x1, 6);  x1 ^= x0;
    x0 += ks0; x1 += ks1 + 3u;
    x0 += x1; x1 = rotl32(x1, 17); x1 ^= x0;
    x0 += x1; x1 = rotl32(x1, 29); x1 ^= x0;
    x0 += x1; x1 = rotl32(x1, 16); x1 ^= x0;
    x0 += x1; x1 = rotl32(x1, 24); x1 ^= x0;
    x0 += ks1; x1 += ks2 + 4u;
    x0 += x1; x1 = rotl32(x1, 13); x1 ^= x0;
    x0 += x1; x1 = rotl32(x1, 15); x1 ^= x0;
    x0 += x1; x1 = rotl32(x1, 26); x1 ^= x0;
    x0 += x1; x1 = rotl32(x1, 6);  x1 ^= x0;
    x0 += ks2; x1 += ks0 + 5u;
}

// ---------- fused node precompute + dist table (f32) ----------
// Blocks [0, NODE_BLKS): 8 nodes per block (measured-best shape).
// Blocks [NODE_BLKS, NODE_BLKS+DIST_BLKS): 8 dist rows each,
// dist_q = dist_table @ Wq[640:768] (verbatim former k_dist body).
__global__ __launch_bounds__(128) void k_node(
    const float* __restrict__ x, const float* __restrict__ aerial,
    const float* __restrict__ Wlin, const float* __restrict__ blin,
    const float* __restrict__ Wq, const float* __restrict__ bq,
    const float* __restrict__ Wv, const float* __restrict__ bv,
    const float* __restrict__ dtab,
    float* __restrict__ xl32, float* __restrict__ q32, float* __restrict__ v32,
    float* __restrict__ dq32) {
    __shared__ float xinT[H_DIM][8];   // [k][m]
    __shared__ float xsT[H_DIM][8];
    __shared__ float aerT[A_DIM][8];
    const int j = threadIdx.x;

    if (blockIdx.x >= NODE_BLKS) {
        // ---- dist path (verbatim former k_dist) ----
        const int n0 = (blockIdx.x - NODE_BLKS) * 8;
#pragma unroll
        for (int m = 0; m < 8; ++m) xinT[j][m] = dtab[(size_t)(n0 + m) * H_DIM + j];
        __syncthreads();
        float acc[8];
#pragma unroll
        for (int m = 0; m < 8; ++m) acc[m] = 0.0f;
        for (int k = 0; k < H_DIM; ++k) {
            float w = Wq[(size_t)(H_DIM + A_DIM + k) * H_DIM + j];
            const float4* xp = (const float4*)&xinT[k][0];
            float4 a0 = xp[0], a1 = xp[1];
            acc[0] = fmaf(a0.x, w, acc[0]); acc[1] = fmaf(a0.y, w, acc[1]);
            acc[2] = fmaf(a0.z, w, acc[2]); acc[3] = fmaf(a0.w, w, acc[3]);
            acc[4] = fmaf(a1.x, w, acc[4]); acc[5] = fmaf(a1.y, w, acc[5]);
            acc[6] = fmaf(a1.z, w, acc[6]); acc[7] = fmaf(a1.w, w, acc[7]);
        }
#pragma unroll
        for (int m = 0; m < 8; ++m) dq32[(size_t)(n0 + m) * H_DIM + j] = acc[m];
        return;
    }

    const int n0 = blockIdx.x * 8;
#pragma unroll
    for (int m = 0; m < 8; ++m) xinT[j][m] = x[(size_t)(n0 + m) * H_DIM + j];
#pragma unroll
    for (int m = 0; m < 8; ++m)
#pragma unroll
        for (int c = 0; c < 4; ++c)
            aerT[c * H_DIM + j][m] = aerial[(size_t)(n0 + m) * A_DIM + c * H_DIM + j];
    __syncthreads();
    // xl = x @ Wlin + blin
    float acc[8];
    {
        float bj = blin[j];
#pragma unroll
        for (int m = 0; m < 8; ++m) acc[m] = bj;
        for (int k = 0; k < H_DIM; ++k) {
            float w = Wlin[k * H_DIM + j];
            const float4* xp = (const float4*)&xinT[k][0];
            float4 a0 = xp[0], a1 = xp[1];
            acc[0] = fmaf(a0.x, w, acc[0]); acc[1] = fmaf(a0.y, w, acc[1]);
            acc[2] = fmaf(a0.z, w, acc[2]); acc[3] = fmaf(a0.w, w, acc[3]);
            acc[4] = fmaf(a1.x, w, acc[4]); acc[5] = fmaf(a1.y, w, acc[5]);
            acc[6] = fmaf(a1.z, w, acc[6]); acc[7] = fmaf(a1.w, w, acc[7]);
        }
    }
#pragma unroll
    for (int m = 0; m < 8; ++m) {
        xsT[j][m] = acc[m];
        xl32[(size_t)(n0 + m) * H_DIM + j] = acc[m];
    }
    __syncthreads();
    // v_node = xl @ Wv + bv
    {
        float bj = bv[j];
        float av[8];
#pragma unroll
        for (int m = 0; m < 8; ++m) av[m] = bj;
        for (int k = 0; k < H_DIM; ++k) {
            float w = Wv[k * H_DIM + j];
            const float4* xp = (const float4*)&xsT[k][0];
            float4 a0 = xp[0], a1 = xp[1];
            av[0] = fmaf(a0.x, w, av[0]); av[1] = fmaf(a0.y, w, av[1]);
            av[2] = fmaf(a0.z, w, av[2]); av[3] = fmaf(a0.w, w, av[3]);
            av[4] = fmaf(a1.x, w, av[4]); av[5] = fmaf(a1.y, w, av[5]);
            av[6] = fmaf(a1.z, w, av[6]); av[7] = fmaf(a1.w, w, av[7]);
        }
#pragma unroll
        for (int m = 0; m < 8; ++m) v32[(size_t)(n0 + m) * H_DIM + j] = av[m];
    }
    // q_node = xl @ Wq[0:128] + aerial @ Wq[128:640] + bq
    {
        float bj = bq[j];
        float aq[8];
#pragma unroll
        for (int m = 0; m < 8; ++m) aq[m] = bj;
        for (int k = 0; k < H_DIM; ++k) {
            float w = Wq[k * H_DIM + j];
            const float4* xp = (const float4*)&xsT[k][0];
            float4 a0 = xp[0], a1 = xp[1];
            aq[0] = fmaf(a0.x, w, aq[0]); aq[1] = fmaf(a0.y, w, aq[1]);
            aq[2] = fmaf(a0.z, w, aq[2]); aq[3] = fmaf(a0.w, w, aq[3]);
            aq[4] = fmaf(a1.x, w, aq[4]); aq[5] = fmaf(a1.y, w, aq[5]);
            aq[6] = fmaf(a1.z, w, aq[6]); aq[7] = fmaf(a1.w, w, aq[7]);
        }
        for (int k = 0; k < A_DIM; ++k) {
            float w = Wq[(size_t)(H_DIM + k) * H_DIM + j];
            const float4* xp = (const float4*)&aerT[k][0];
            float4 a0 = xp[0], a1 = xp[1];
            aq[0] = fmaf(a0.x, w, aq[0]); aq[1] = fmaf(a0.y, w, aq[1]);
            aq[2] = fmaf(a0.z, w, aq[2]); aq[3] = fmaf(a0.w, w, aq[3]);
            aq[4] = fmaf(a1.x, w, aq[4]); aq[5] = fmaf(a1.y, w, aq[5]);
            aq[6] = fmaf(a1.z, w, aq[6]); aq[7] = fmaf(a1.w, w, aq[7]);
        }
#pragma unroll
        for (int m = 0; m < 8; ++m) q32[(size_t)(n0 + m) * H_DIM + j] = aq[m];
    }
}

__device__ __forceinline__ int bin1_of(float s) {
    float t = (s - LO_F) * SCALE1;
    int b = (int)t;
    return min(max(b, 0), NB1 - 1);
}
__device__ __forceinline__ int bin2_of(float s, int b1) {
    float t = (s - LO_F) * SCALE1;
    float frac = t - (float)b1;
    int b = (int)(frac * (float)NB2);
    return min(max(b, 0), NB2 - 1);
}

// ---------- per-edge score: 32-lane group handles 4 edges (measured best) ----------
// 12 independent float4 gathers in flight; butterfly reduces 4 sums
// simultaneously; tail (threefry inline, sqrt/log/key/hist) runs on lanes
// 0-3 in parallel. Per-edge arithmetic bit-identical to the original;
// inline threefry produces the exact bits the former k_rand wrote.
__global__ __launch_bounds__(256) void k_score(
    const int* __restrict__ ei, const int* __restrict__ dist,
    const float* __restrict__ q32, const float* __restrict__ v32,
    const float* __restrict__ dq32,
    unsigned long long* __restrict__ keys, float* __restrict__ s32o,
    unsigned* __restrict__ hist1) {
    const int g = threadIdx.x >> 5, lane = threadIdx.x & 31;
    const int e0 = blockIdx.x * 32 + g * 4;

    const int s0 = ei[e0 + 0], s1 = ei[e0 + 1], s2 = ei[e0 + 2], s3 = ei[e0 + 3];
    const int t0 = ei[E_EDGES + e0 + 0], t1 = ei[E_EDGES + e0 + 1];
    const int t2 = ei[E_EDGES + e0 + 2], t3 = ei[E_EDGES + e0 + 3];
    const int d0 = dist[e0 + 0] / 50, d1 = dist[e0 + 1] / 50;
    const int d2 = dist[e0 + 2] / 50, d3 = dist[e0 + 3] / 50;

    float4 q0 = ((const float4*)(q32 + (size_t)s0 * H_DIM))[lane];
    float4 q1 = ((const float4*)(q32 + (size_t)s1 * H_DIM))[lane];
    float4 q2 = ((const float4*)(q32 + (size_t)s2 * H_DIM))[lane];
    float4 q3 = ((const float4*)(q32 + (size_t)s3 * H_DIM))[lane];
    float4 v0 = ((const float4*)(v32 + (size_t)t0 * H_DIM))[lane];
    float4 v1 = ((const float4*)(v32 + (size_t)t1 * H_DIM))[lane];
    float4 v2 = ((const float4*)(v32 + (size_t)t2 * H_DIM))[lane];
    float4 v3 = ((const float4*)(v32 + (size_t)t3 * H_DIM))[lane];
    float4 w0 = ((const float4*)(dq32 + (size_t)d0 * H_DIM))[lane];
    float4 w1 = ((const float4*)(dq32 + (size_t)d1 * H_DIM))[lane];
    float4 w2 = ((const float4*)(dq32 + (size_t)d2 * H_DIM))[lane];
    float4 w3 = ((const float4*)(dq32 + (size_t)d3 * H_DIM))[lane];

    float ax, ay, az, aw;
    ax = q0.x + w0.x - v0.x; ay = q0.y + w0.y - v0.y;
    az = q0.z + w0.z - v0.z; aw = q0.w + w0.w - v0.w;
    float ss0 = fmaf(ax, ax, fmaf(ay, ay, fmaf(az, az, aw * aw)));
    ax = q1.x + w1.x - v1.x; ay = q1.y + w1.y - v1.y;
    az = q1.z + w1.z - v1.z; aw = q1.w + w1.w - v1.w;
    float ss1 = fmaf(ax, ax, fmaf(ay, ay, fmaf(az, az, aw * aw)));
    ax = q2.x + w2.x - v2.x; ay = q2.y + w2.y - v2.y;
    az = q2.z + w2.z - v2.z; aw = q2.w + w2.w - v2.w;
    float ss2 = fmaf(ax, ax, fmaf(ay, ay, fmaf(az, az, aw * aw)));
    ax = q3.x + w3.x - v3.x; ay = q3.y + w3.y - v3.y;
    az = q3.z + w3.z - v3.z; aw = q3.w + w3.w - v3.w;
    float ss3 = fmaf(ax, ax, fmaf(ay, ay, fmaf(az, az, aw * aw)));

#pragma unroll
    for (int o = 16; o > 0; o >>= 1) {
        ss0 += __shfl_xor(ss0, o, 64);
        ss1 += __shfl_xor(ss1, o, 64);
        ss2 += __shfl_xor(ss2, o, 64);
        ss3 += __shfl_xor(ss3, o, 64);
    }
    if (lane < 4) {
        float ssv = (lane == 0) ? ss0 : (lane == 1) ? ss1 : (lane == 2) ? ss2 : ss3;
        const int e = e0 + lane;
        // inline JAX threefry: counter=(0,e), key=(0,42), bits = out0^out1
        uint32_t x0r = 0u, x1r = (uint32_t)e;
        threefry2x32(0u, 42u, x0r, x1r);
        uint32_t bits = x0r ^ x1r;
        float uu = __uint_as_float((bits >> 9) | 0x3f800000u) - 1.0f;
        float nrm = sqrtf(ssv);
        float a = -logf(uu + 1e-20f);
        float gm = -logf(a + 1e-20f);
        float score = gm - nrm;
        int ib = __float_as_int(score);
        unsigned m32 = (ib < 0) ? ~(unsigned)ib : ((unsigned)ib | 0x80000000u);
        // unique key: score-ordered high bits, lower edge index wins ties
        keys[e] = ((unsigned long long)m32 << 32) | (unsigned)(0xFFFFFFFFu - (unsigned)e);
        s32o[e] = score;
        atomicAdd(&hist1[bin1_of(score)], 1u);
    }
}

__global__ __launch_bounds__(256) void k_hist2(const float* __restrict__ s32,
                                               const SelState* __restrict__ st,
                                               unsigned* __restrict__ hist2) {
    int e = blockIdx.x * 256 + threadIdx.x;
    if (e >= E_EDGES) return;
    float s = s32[e];
    int b1 = bin1_of(s);
    if (b1 != st->b1) return;
    atomicAdd(&hist2[bin2_of(s, b1)], 1u);
}

// descending scan over 16384 bins to locate the bin holding the target rank
__global__ __launch_bounds__(256) void k_scan(const unsigned* __restrict__ hist,
                                              SelState* st, int phase) {
    __shared__ unsigned csum[256];
    __shared__ unsigned bins[64];
    __shared__ int selc;
    __shared__ unsigned cumbase;
    const int t = threadIdx.x;
    const unsigned target = (phase == 1) ? K_SEL : st->r1;
    unsigned s = 0;
    for (int i = 0; i < 64; ++i) s += hist[t * 64 + i];
    csum[t] = s;
    __syncthreads();
    if (t == 0) {
        unsigned cum = 0; int c = 255;
        for (; c >= 0; --c) {
            if (cum + csum[c] >= target) break;
            cum += csum[c];
        }
        selc = c; cumbase = cum;
    }
    __syncthreads();
    if (t < 64) bins[t] = hist[selc * 64 + t];
    __syncthreads();
    if (t == 0) {
        unsigned cum = cumbase; int b = -1;
        for (int i = 63; i >= 0; --i) {
            if (cum + bins[i] >= target) { b = selc * 64 + i; break; }
            cum += bins[i];
        }
        unsigned r = target - cum;
        if (phase == 1) { st->b1 = b; st->cum1 = cum; st->r1 = r; }
        else           { st->b2 = b; st->cum2 = cum; st->r2 = r; }
    }
}

__global__ __launch_bounds__(256) void k_collect(
    const float* __restrict__ s32, const unsigned long long* __restrict__ keys,
    const SelState* __restrict__ st, unsigned long long* __restrict__ cand,
    unsigned* __restrict__ cnt) {
    int e = blockIdx.x * 256 + threadIdx.x;
    if (e >= E_EDGES) return;
    float s = s32[e];
    int b1 = bin1_of(s);
    if (b1 != st->b1) return;
    if (bin2_of(s, b1) != st->b2) return;
    unsigned p = atomicAdd(cnt, 1u);
    if (p < CAND_MAX) cand[p] = keys[e];
}

// T = r2-th largest key among candidates (keys are unique)
__global__ __launch_bounds__(256) void k_thresh(
    const unsigned long long* __restrict__ cand, const unsigned* __restrict__ cnt,
    SelState* st) {
    int c = (int)min(*cnt, (unsigned)CAND_MAX);
    unsigned r2 = st->r2;
    for (int i = threadIdx.x; i < c; i += blockDim.x) {
        unsigned long long ki = cand[i];
        unsigned g = 0;
        for (int j = 0; j < c; ++j) g += (cand[j] > ki);
        if (g == r2 - 1) st->T = ki;
    }
}

// wave per edge: key >= T selects; scatter xl[src] into msg[tgt] + deg
__global__ __launch_bounds__(256) void k_scatter(
    const int* __restrict__ ei, const unsigned long long* __restrict__ keys,
    const SelState* __restrict__ st, const float* __restrict__ xl32,
    float* __restrict__ msg, float* __restrict__ deg) {
    const int wid = threadIdx.x >> 6, lane = threadIdx.x & 63;
    const int e = blockIdx.x * 4 + wid;
    if (keys[e] >= st->T) {
        int sidx = ei[e], tidx = ei[E_EDGES + e];
        const float* xp = xl32 + (size_t)sidx * H_DIM;
        float* mp = msg + (size_t)tidx * H_DIM;
        const int h = lane * 2;
        atomicAdd(&mp[h], xp[h]);
        atomicAdd(&mp[h + 1], xp[h + 1]);
        if (lane == 0) atomicAdd(&deg[tidx], 1.0f);
    }
}

// out = (msg/max(deg,1)) @ Wl + bl + xl @ Wr
__global__ __launch_bounds__(128) void k_out(
    const float* __restrict__ msg, const float* __restrict__ deg,
    const float* __restrict__ xl32, const float* __restrict__ Wl,
    const float* __restrict__ bl, const float* __restrict__ Wr,
    float* __restrict__ out) {
    __shared__ float axT[H_DIM][8];
    __shared__ float xxT[H_DIM][8];
    const int j = threadIdx.x;
    const int n0 = blockIdx.x * 8;
#pragma unroll
    for (int m = 0; m < 8; ++m) {
        float d = fmaxf(deg[n0 + m], 1.0f);
        axT[j][m] = msg[(size_t)(n0 + m) * H_DIM + j] / d;
        xxT[j][m] = xl32[(size_t)(n0 + m) * H_DIM + j];
    }
    __syncthreads();
    float acc[8];
    float bj = bl[j];
#pragma unroll
    for (int m = 0; m < 8; ++m) acc[m] = bj;
    for (int k = 0; k < H_DIM; ++k) {
        float wl = Wl[k * H_DIM + j];
        float wr = Wr[k * H_DIM + j];
        const float4* ap = (const float4*)&axT[k][0];
        const float4* xp = (const float4*)&xxT[k][0];
        float4 a0 = ap[0], a1 = ap[1];
        float4 x0 = xp[0], x1 = xp[1];
        acc[0] = fmaf(a0.x, wl, fmaf(x0.x, wr, acc[0]));
        acc[1] = fmaf(a0.y, wl, fmaf(x0.y, wr, acc[1]));
        acc[2] = fmaf(a0.z, wl, fmaf(x0.z, wr, acc[2]));
        acc[3] = fmaf(a0.w, wl, fmaf(x0.w, wr, acc[3]));
        acc[4] = fmaf(a1.x, wl, fmaf(x1.x, wr, acc[4]));
        acc[5] = fmaf(a1.y, wl, fmaf(x1.y, wr, acc[5]));
        acc[6] = fmaf(a1.z, wl, fmaf(x1.z, wr, acc[6]));
        acc[7] = fmaf(a1.w, wl, fmaf(x1.w, wr, acc[7]));
    }
#pragma unroll
    for (int m = 0; m < 8; ++m) out[(size_t)(n0 + m) * H_DIM + j] = acc[m];
}

extern "C" void kernel_launch(void* const* d_in, const int* in_sizes, int n_in,
                              void* d_out, int out_size, void* d_ws, size_t ws_size,
                              hipStream_t stream) {
    const float* x      = (const float*)d_in[0];
    const int*   ei     = (const int*)d_in[1];
    const int*   dist   = (const int*)d_in[2];
    const float* aerial = (const float*)d_in[3];
    const float* Wlin   = (const float*)d_in[4];
    const float* blin   = (const float*)d_in[5];
    const float* Wq     = (const float*)d_in[6];
    const float* bq     = (const float*)d_in[7];
    const float* Wv     = (const float*)d_in[8];
    const float* bv     = (const float*)d_in[9];
    const float* dtab   = (const float*)d_in[10];
    const float* Wl     = (const float*)d_in[11];
    const float* bl     = (const float*)d_in[12];
    const float* Wr     = (const float*)d_in[13];
    float* out = (float*)d_out;

    char* ws = (char*)d_ws;
    size_t off = 0;
    auto alloc = [&](size_t bytes) -> void* {
        void* p = ws + off;
        off += (bytes + 255) & ~(size_t)255;
        return p;
    };
    float* q32  = (float*)alloc((size_t)N_NODES * H_DIM * 4);
    float* v32  = (float*)alloc((size_t)N_NODES * H_DIM * 4);
    float* dq32 = (float*)alloc((size_t)NEMB_N * H_DIM * 4);
    unsigned long long* keys = (unsigned long long*)alloc((size_t)E_EDGES * 8);
    float* xl32 = (float*)alloc((size_t)N_NODES * H_DIM * 4);
    float* s32  = (float*)alloc((size_t)E_EDGES * 4);
    char* zbase = ws + off;
    float* msg  = (float*)alloc((size_t)N_NODES * H_DIM * 4);
    float* deg  = (float*)alloc((size_t)N_NODES * 4);
    unsigned* hist1 = (unsigned*)alloc((size_t)NB1 * 4);
    unsigned* hist2 = (unsigned*)alloc((size_t)NB2 * 4);
    unsigned long long* cand = (unsigned long long*)alloc((size_t)CAND_MAX * 8);
    unsigned* counters = (unsigned*)alloc(256);   // [0]=candCount
    SelState* st = (SelState*)alloc(256);
    size_t zlen = (size_t)((ws + off) - zbase);

    hipMemsetAsync(zbase, 0, zlen, stream);

    k_node<<<NODE_BLKS + DIST_BLKS, 128, 0, stream>>>(
        x, aerial, Wlin, blin, Wq, bq, Wv, bv, dtab, xl32, q32, v32, dq32);
    k_score<<<E_EDGES / 32, 256, 0, stream>>>(ei, dist, q32, v32, dq32,
                                              keys, s32, hist1);
    k_scan<<<1, 256, 0, stream>>>(hist1, st, 1);
    k_hist2<<<(E_EDGES + 255) / 256, 256, 0, stream>>>(s32, st, hist2);
    k_scan<<<1, 256, 0, stream>>>(hist2, st, 2);
    k_collect<<<(E_EDGES + 255) / 256, 256, 0, stream>>>(s32, keys, st, cand, &counters[0]);
    k_thresh<<<1, 256, 0, stream>>>(cand, &counters[0], st);
    k_scatter<<<E_EDGES / 4, 256, 0, stream>>>(ei, keys, st, xl32, msg, deg);
    k_out<<<N_NODES / 8, 128, 0, stream>>>(msg, deg, xl32, Wl, bl, Wr, out);
}

// Round 10
// 520.565 us; speedup vs baseline: 1.0756x; 1.0019x over previous
//
#include <hip/hip_runtime.h>
#include <stdint.h>

#define N_NODES 20000
#define E_EDGES 320000
#define H_DIM 128
#define A_DIM 512
#define NEMB_N 400
#define K_SEL 80000u
#define NB1 16384
#define NB2 16384
#define CAND_MAX 8192
#define LO_F (-128.0f)
#define SCALE1 (16384.0f / 160.0f)   /* bins over [-128, 32) */

#define NODE_BLKS (N_NODES / 8)      /* 2500 */
#define DIST_BLKS (NEMB_N / 8)       /* 50   */

struct SelState {
    int b1; unsigned cum1; unsigned r1;
    int b2; unsigned cum2; unsigned r2;
    unsigned long long T;
};

// clang-native float vector (valid for __builtin_nontemporal_load;
// HIP_vector_type float4 is not)
typedef __attribute__((ext_vector_type(4))) float f32x4;

__device__ __forceinline__ float4 ntload4(const float* p) {
    f32x4 v = __builtin_nontemporal_load((const f32x4*)p);
    float4 r; r.x = v.x; r.y = v.y; r.z = v.z; r.w = v.w;
    return r;
}

// ---------------- threefry2x32 (JAX, 20 rounds) ----------------
__device__ __forceinline__ uint32_t rotl32(uint32_t x, int r) {
    return (x << r) | (x >> (32 - r));
}

__device__ __forceinline__ void threefry2x32(uint32_t k0, uint32_t k1,
                                             uint32_t& x0, uint32_t& x1) {
    uint32_t ks0 = k0, ks1 = k1, ks2 = k0 ^ k1 ^ 0x1BD11BDAu;
    x0 += ks0; x1 += ks1;
    x0 += x1; x1 = rotl32(x1, 13); x1 ^= x0;
    x0 += x1; x1 = rotl32(x1, 15); x1 ^= x0;
    x0 += x1; x1 = rotl32(x1, 26); x1 ^= x0;
    x0 += x1; x1 = rotl32(x1, 6);  x1 ^= x0;
    x0 += ks1; x1 += ks2 + 1u;
    x0 += x1; x1 = rotl32(x1, 17); x1 ^= x0;
    x0 += x1; x1 = rotl32(x1, 29); x1 ^= x0;
    x0 += x1; x1 = rotl32(x1, 16); x1 ^= x0;
    x0 += x1; x1 = rotl32(x1, 24); x1 ^= x0;
    x0 += ks2; x1 += ks0 + 2u;
    x0 += x1; x1 = rotl32(x1, 13); x1 ^= x0;
    x0 += x1; x1 = rotl32(x1, 15); x1 ^= x0;
    x0 += x1; x1 = rotl32(x1, 26); x1 ^= x0;
    x0 += x1; x1 = rotl32(x1, 6);  x1 ^= x0;
    x0 += ks0; x1 += ks1 + 3u;
    x0 += x1; x1 = rotl32(x1, 17); x1 ^= x0;
    x0 += x1; x1 = rotl32(x1, 29); x1 ^= x0;
    x0 += x1; x1 = rotl32(x1, 16); x1 ^= x0;
    x0 += x1; x1 = rotl32(x1, 24); x1 ^= x0;
    x0 += ks1; x1 += ks2 + 4u;
    x0 += x1; x1 = rotl32(x1, 13); x1 ^= x0;
    x0 += x1; x1 = rotl32(x1, 15); x1 ^= x0;
    x0 += x1; x1 = rotl32(x1, 26); x1 ^= x0;
    x0 += x1; x1 = rotl32(x1, 6);  x1 ^= x0;
    x0 += ks2; x1 += ks0 + 5u;
}

// ---------- fused node precompute + dist table (f32) ----------
// Blocks [0, NODE_BLKS): 8 nodes per block (measured-best shape).
// Blocks [NODE_BLKS, NODE_BLKS+DIST_BLKS): 8 dist rows each,
// dist_q = dist_table @ Wq[640:768] (verbatim former k_dist body).
__global__ __launch_bounds__(128) void k_node(
    const float* __restrict__ x, const float* __restrict__ aerial,
    const float* __restrict__ Wlin, const float* __restrict__ blin,
    const float* __restrict__ Wq, const float* __restrict__ bq,
    const float* __restrict__ Wv, const float* __restrict__ bv,
    const float* __restrict__ dtab,
    float* __restrict__ xl32, float* __restrict__ q32, float* __restrict__ v32,
    float* __restrict__ dq32) {
    __shared__ float xinT[H_DIM][8];   // [k][m]
    __shared__ float xsT[H_DIM][8];
    __shared__ float aerT[A_DIM][8];
    const int j = threadIdx.x;

    if (blockIdx.x >= NODE_BLKS) {
        // ---- dist path (verbatim former k_dist) ----
        const int n0 = (blockIdx.x - NODE_BLKS) * 8;
#pragma unroll
        for (int m = 0; m < 8; ++m) xinT[j][m] = dtab[(size_t)(n0 + m) * H_DIM + j];
        __syncthreads();
        float acc[8];
#pragma unroll
        for (int m = 0; m < 8; ++m) acc[m] = 0.0f;
        for (int k = 0; k < H_DIM; ++k) {
            float w = Wq[(size_t)(H_DIM + A_DIM + k) * H_DIM + j];
            const float4* xp = (const float4*)&xinT[k][0];
            float4 a0 = xp[0], a1 = xp[1];
            acc[0] = fmaf(a0.x, w, acc[0]); acc[1] = fmaf(a0.y, w, acc[1]);
            acc[2] = fmaf(a0.z, w, acc[2]); acc[3] = fmaf(a0.w, w, acc[3]);
            acc[4] = fmaf(a1.x, w, acc[4]); acc[5] = fmaf(a1.y, w, acc[5]);
            acc[6] = fmaf(a1.z, w, acc[6]); acc[7] = fmaf(a1.w, w, acc[7]);
        }
#pragma unroll
        for (int m = 0; m < 8; ++m) dq32[(size_t)(n0 + m) * H_DIM + j] = acc[m];
        return;
    }

    const int n0 = blockIdx.x * 8;
#pragma unroll
    for (int m = 0; m < 8; ++m) xinT[j][m] = x[(size_t)(n0 + m) * H_DIM + j];
#pragma unroll
    for (int m = 0; m < 8; ++m)
#pragma unroll
        for (int c = 0; c < 4; ++c)
            aerT[c * H_DIM + j][m] = aerial[(size_t)(n0 + m) * A_DIM + c * H_DIM + j];
    __syncthreads();
    // xl = x @ Wlin + blin
    float acc[8];
    {
        float bj = blin[j];
#pragma unroll
        for (int m = 0; m < 8; ++m) acc[m] = bj;
        for (int k = 0; k < H_DIM; ++k) {
            float w = Wlin[k * H_DIM + j];
            const float4* xp = (const float4*)&xinT[k][0];
            float4 a0 = xp[0], a1 = xp[1];
            acc[0] = fmaf(a0.x, w, acc[0]); acc[1] = fmaf(a0.y, w, acc[1]);
            acc[2] = fmaf(a0.z, w, acc[2]); acc[3] = fmaf(a0.w, w, acc[3]);
            acc[4] = fmaf(a1.x, w, acc[4]); acc[5] = fmaf(a1.y, w, acc[5]);
            acc[6] = fmaf(a1.z, w, acc[6]); acc[7] = fmaf(a1.w, w, acc[7]);
        }
    }
#pragma unroll
    for (int m = 0; m < 8; ++m) {
        xsT[j][m] = acc[m];
        xl32[(size_t)(n0 + m) * H_DIM + j] = acc[m];
    }
    __syncthreads();
    // v_node = xl @ Wv + bv
    {
        float bj = bv[j];
        float av[8];
#pragma unroll
        for (int m = 0; m < 8; ++m) av[m] = bj;
        for (int k = 0; k < H_DIM; ++k) {
            float w = Wv[k * H_DIM + j];
            const float4* xp = (const float4*)&xsT[k][0];
            float4 a0 = xp[0], a1 = xp[1];
            av[0] = fmaf(a0.x, w, av[0]); av[1] = fmaf(a0.y, w, av[1]);
            av[2] = fmaf(a0.z, w, av[2]); av[3] = fmaf(a0.w, w, av[3]);
            av[4] = fmaf(a1.x, w, av[4]); av[5] = fmaf(a1.y, w, av[5]);
            av[6] = fmaf(a1.z, w, av[6]); av[7] = fmaf(a1.w, w, av[7]);
        }
#pragma unroll
        for (int m = 0; m < 8; ++m) v32[(size_t)(n0 + m) * H_DIM + j] = av[m];
    }
    // q_node = xl @ Wq[0:128] + aerial @ Wq[128:640] + bq
    {
        float bj = bq[j];
        float aq[8];
#pragma unroll
        for (int m = 0; m < 8; ++m) aq[m] = bj;
        for (int k = 0; k < H_DIM; ++k) {
            float w = Wq[k * H_DIM + j];
            const float4* xp = (const float4*)&xsT[k][0];
            float4 a0 = xp[0], a1 = xp[1];
            aq[0] = fmaf(a0.x, w, aq[0]); aq[1] = fmaf(a0.y, w, aq[1]);
            aq[2] = fmaf(a0.z, w, aq[2]); aq[3] = fmaf(a0.w, w, aq[3]);
            aq[4] = fmaf(a1.x, w, aq[4]); aq[5] = fmaf(a1.y, w, aq[5]);
            aq[6] = fmaf(a1.z, w, aq[6]); aq[7] = fmaf(a1.w, w, aq[7]);
        }
        for (int k = 0; k < A_DIM; ++k) {
            float w = Wq[(size_t)(H_DIM + k) * H_DIM + j];
            const float4* xp = (const float4*)&aerT[k][0];
            float4 a0 = xp[0], a1 = xp[1];
            aq[0] = fmaf(a0.x, w, aq[0]); aq[1] = fmaf(a0.y, w, aq[1]);
            aq[2] = fmaf(a0.z, w, aq[2]); aq[3] = fmaf(a0.w, w, aq[3]);
            aq[4] = fmaf(a1.x, w, aq[4]); aq[5] = fmaf(a1.y, w, aq[5]);
            aq[6] = fmaf(a1.z, w, aq[6]); aq[7] = fmaf(a1.w, w, aq[7]);
        }
#pragma unroll
        for (int m = 0; m < 8; ++m) q32[(size_t)(n0 + m) * H_DIM + j] = aq[m];
    }
}

__device__ __forceinline__ int bin1_of(float s) {
    float t = (s - LO_F) * SCALE1;
    int b = (int)t;
    return min(max(b, 0), NB1 - 1);
}
__device__ __forceinline__ int bin2_of(float s, int b1) {
    float t = (s - LO_F) * SCALE1;
    float frac = t - (float)b1;
    int b = (int)(frac * (float)NB2);
    return min(max(b, 0), NB2 - 1);
}

// ---------- per-edge score: 32-lane group handles 4 edges ----------
// q/v row gathers use NONTEMPORAL loads (via clang ext_vector f32x4):
// q32/v32 are 10 MB randomly indexed (L1 hit ~0%); the measured limiter
// is ~64-72 cyc per random 512B row, invariant to packing/locality
// (rounds 1/3/5) -> L1/TCP miss-allocation rate. nt skips L1 allocation.
// dq32 (200 KB, reused) stays cached. Same addresses/bytes -> bit-exact.
__global__ __launch_bounds__(256) void k_score(
    const int* __restrict__ ei, const int* __restrict__ dist,
    const float* __restrict__ q32, const float* __restrict__ v32,
    const float* __restrict__ dq32,
    unsigned long long* __restrict__ keys, float* __restrict__ s32o,
    unsigned* __restrict__ hist1) {
    const int g = threadIdx.x >> 5, lane = threadIdx.x & 31;
    const int e0 = blockIdx.x * 32 + g * 4;

    const int s0 = ei[e0 + 0], s1 = ei[e0 + 1], s2 = ei[e0 + 2], s3 = ei[e0 + 3];
    const int t0 = ei[E_EDGES + e0 + 0], t1 = ei[E_EDGES + e0 + 1];
    const int t2 = ei[E_EDGES + e0 + 2], t3 = ei[E_EDGES + e0 + 3];
    const int d0 = dist[e0 + 0] / 50, d1 = dist[e0 + 1] / 50;
    const int d2 = dist[e0 + 2] / 50, d3 = dist[e0 + 3] / 50;

    float4 q0 = ntload4(q32 + (size_t)s0 * H_DIM + lane * 4);
    float4 q1 = ntload4(q32 + (size_t)s1 * H_DIM + lane * 4);
    float4 q2 = ntload4(q32 + (size_t)s2 * H_DIM + lane * 4);
    float4 q3 = ntload4(q32 + (size_t)s3 * H_DIM + lane * 4);
    float4 v0 = ntload4(v32 + (size_t)t0 * H_DIM + lane * 4);
    float4 v1 = ntload4(v32 + (size_t)t1 * H_DIM + lane * 4);
    float4 v2 = ntload4(v32 + (size_t)t2 * H_DIM + lane * 4);
    float4 v3 = ntload4(v32 + (size_t)t3 * H_DIM + lane * 4);
    float4 w0 = ((const float4*)(dq32 + (size_t)d0 * H_DIM))[lane];
    float4 w1 = ((const float4*)(dq32 + (size_t)d1 * H_DIM))[lane];
    float4 w2 = ((const float4*)(dq32 + (size_t)d2 * H_DIM))[lane];
    float4 w3 = ((const float4*)(dq32 + (size_t)d3 * H_DIM))[lane];

    float ax, ay, az, aw;
    ax = q0.x + w0.x - v0.x; ay = q0.y + w0.y - v0.y;
    az = q0.z + w0.z - v0.z; aw = q0.w + w0.w - v0.w;
    float ss0 = fmaf(ax, ax, fmaf(ay, ay, fmaf(az, az, aw * aw)));
    ax = q1.x + w1.x - v1.x; ay = q1.y + w1.y - v1.y;
    az = q1.z + w1.z - v1.z; aw = q1.w + w1.w - v1.w;
    float ss1 = fmaf(ax, ax, fmaf(ay, ay, fmaf(az, az, aw * aw)));
    ax = q2.x + w2.x - v2.x; ay = q2.y + w2.y - v2.y;
    az = q2.z + w2.z - v2.z; aw = q2.w + w2.w - v2.w;
    float ss2 = fmaf(ax, ax, fmaf(ay, ay, fmaf(az, az, aw * aw)));
    ax = q3.x + w3.x - v3.x; ay = q3.y + w3.y - v3.y;
    az = q3.z + w3.z - v3.z; aw = q3.w + w3.w - v3.w;
    float ss3 = fmaf(ax, ax, fmaf(ay, ay, fmaf(az, az, aw * aw)));

#pragma unroll
    for (int o = 16; o > 0; o >>= 1) {
        ss0 += __shfl_xor(ss0, o, 64);
        ss1 += __shfl_xor(ss1, o, 64);
        ss2 += __shfl_xor(ss2, o, 64);
        ss3 += __shfl_xor(ss3, o, 64);
    }
    if (lane < 4) {
        float ssv = (lane == 0) ? ss0 : (lane == 1) ? ss1 : (lane == 2) ? ss2 : ss3;
        const int e = e0 + lane;
        // inline JAX threefry: counter=(0,e), key=(0,42), bits = out0^out1
        uint32_t x0r = 0u, x1r = (uint32_t)e;
        threefry2x32(0u, 42u, x0r, x1r);
        uint32_t bits = x0r ^ x1r;
        float uu = __uint_as_float((bits >> 9) | 0x3f800000u) - 1.0f;
        float nrm = sqrtf(ssv);
        float a = -logf(uu + 1e-20f);
        float gm = -logf(a + 1e-20f);
        float score = gm - nrm;
        int ib = __float_as_int(score);
        unsigned m32 = (ib < 0) ? ~(unsigned)ib : ((unsigned)ib | 0x80000000u);
        // unique key: score-ordered high bits, lower edge index wins ties
        keys[e] = ((unsigned long long)m32 << 32) | (unsigned)(0xFFFFFFFFu - (unsigned)e);
        s32o[e] = score;
        atomicAdd(&hist1[bin1_of(score)], 1u);
    }
}

__global__ __launch_bounds__(256) void k_hist2(const float* __restrict__ s32,
                                               const SelState* __restrict__ st,
                                               unsigned* __restrict__ hist2) {
    int e = blockIdx.x * 256 + threadIdx.x;
    if (e >= E_EDGES) return;
    float s = s32[e];
    int b1 = bin1_of(s);
    if (b1 != st->b1) return;
    atomicAdd(&hist2[bin2_of(s, b1)], 1u);
}

// descending scan over 16384 bins to locate the bin holding the target rank
__global__ __launch_bounds__(256) void k_scan(const unsigned* __restrict__ hist,
                                              SelState* st, int phase) {
    __shared__ unsigned csum[256];
    __shared__ unsigned bins[64];
    __shared__ int selc;
    __shared__ unsigned cumbase;
    const int t = threadIdx.x;
    const unsigned target = (phase == 1) ? K_SEL : st->r1;
    unsigned s = 0;
    for (int i = 0; i < 64; ++i) s += hist[t * 64 + i];
    csum[t] = s;
    __syncthreads();
    if (t == 0) {
        unsigned cum = 0; int c = 255;
        for (; c >= 0; --c) {
            if (cum + csum[c] >= target) break;
            cum += csum[c];
        }
        selc = c; cumbase = cum;
    }
    __syncthreads();
    if (t < 64) bins[t] = hist[selc * 64 + t];
    __syncthreads();
    if (t == 0) {
        unsigned cum = cumbase; int b = -1;
        for (int i = 63; i >= 0; --i) {
            if (cum + bins[i] >= target) { b = selc * 64 + i; break; }
            cum += bins[i];
        }
        unsigned r = target - cum;
        if (phase == 1) { st->b1 = b; st->cum1 = cum; st->r1 = r; }
        else           { st->b2 = b; st->cum2 = cum; st->r2 = r; }
    }
}

__global__ __launch_bounds__(256) void k_collect(
    const float* __restrict__ s32, const unsigned long long* __restrict__ keys,
    const SelState* __restrict__ st, unsigned long long* __restrict__ cand,
    unsigned* __restrict__ cnt) {
    int e = blockIdx.x * 256 + threadIdx.x;
    if (e >= E_EDGES) return;
    float s = s32[e];
    int b1 = bin1_of(s);
    if (b1 != st->b1) return;
    if (bin2_of(s, b1) != st->b2) return;
    unsigned p = atomicAdd(cnt, 1u);
    if (p < CAND_MAX) cand[p] = keys[e];
}

// T = r2-th largest key among candidates (keys are unique)
__global__ __launch_bounds__(256) void k_thresh(
    const unsigned long long* __restrict__ cand, const unsigned* __restrict__ cnt,
    SelState* st) {
    int c = (int)min(*cnt, (unsigned)CAND_MAX);
    unsigned r2 = st->r2;
    for (int i = threadIdx.x; i < c; i += blockDim.x) {
        unsigned long long ki = cand[i];
        unsigned g = 0;
        for (int j = 0; j < c; ++j) g += (cand[j] > ki);
        if (g == r2 - 1) st->T = ki;
    }
}

// wave per edge: key >= T selects; scatter xl[src] into msg[tgt] + deg
__global__ __launch_bounds__(256) void k_scatter(
    const int* __restrict__ ei, const unsigned long long* __restrict__ keys,
    const SelState* __restrict__ st, const float* __restrict__ xl32,
    float* __restrict__ msg, float* __restrict__ deg) {
    const int wid = threadIdx.x >> 6, lane = threadIdx.x & 63;
    const int e = blockIdx.x * 4 + wid;
    if (keys[e] >= st->T) {
        int sidx = ei[e], tidx = ei[E_EDGES + e];
        const float* xp = xl32 + (size_t)sidx * H_DIM;
        float* mp = msg + (size_t)tidx * H_DIM;
        const int h = lane * 2;
        atomicAdd(&mp[h], xp[h]);
        atomicAdd(&mp[h + 1], xp[h + 1]);
        if (lane == 0) atomicAdd(&deg[tidx], 1.0f);
    }
}

// out = (msg/max(deg,1)) @ Wl + bl + xl @ Wr
__global__ __launch_bounds__(128) void k_out(
    const float* __restrict__ msg, const float* __restrict__ deg,
    const float* __restrict__ xl32, const float* __restrict__ Wl,
    const float* __restrict__ bl, const float* __restrict__ Wr,
    float* __restrict__ out) {
    __shared__ float axT[H_DIM][8];
    __shared__ float xxT[H_DIM][8];
    const int j = threadIdx.x;
    const int n0 = blockIdx.x * 8;
#pragma unroll
    for (int m = 0; m < 8; ++m) {
        float d = fmaxf(deg[n0 + m], 1.0f);
        axT[j][m] = msg[(size_t)(n0 + m) * H_DIM + j] / d;
        xxT[j][m] = xl32[(size_t)(n0 + m) * H_DIM + j];
    }
    __syncthreads();
    float acc[8];
    float bj = bl[j];
#pragma unroll
    for (int m = 0; m < 8; ++m) acc[m] = bj;
    for (int k = 0; k < H_DIM; ++k) {
        float wl = Wl[k * H_DIM + j];
        float wr = Wr[k * H_DIM + j];
        const float4* ap = (const float4*)&axT[k][0];
        const float4* xp = (const float4*)&xxT[k][0];
        float4 a0 = ap[0], a1 = ap[1];
        float4 x0 = xp[0], x1 = xp[1];
        acc[0] = fmaf(a0.x, wl, fmaf(x0.x, wr, acc[0]));
        acc[1] = fmaf(a0.y, wl, fmaf(x0.y, wr, acc[1]));
        acc[2] = fmaf(a0.z, wl, fmaf(x0.z, wr, acc[2]));
        acc[3] = fmaf(a0.w, wl, fmaf(x0.w, wr, acc[3]));
        acc[4] = fmaf(a1.x, wl, fmaf(x1.x, wr, acc[4]));
        acc[5] = fmaf(a1.y, wl, fmaf(x1.y, wr, acc[5]));
        acc[6] = fmaf(a1.z, wl, fmaf(x1.z, wr, acc[6]));
        acc[7] = fmaf(a1.w, wl, fmaf(x1.w, wr, acc[7]));
    }
#pragma unroll
    for (int m = 0; m < 8; ++m) out[(size_t)(n0 + m) * H_DIM + j] = acc[m];
}

extern "C" void kernel_launch(void* const* d_in, const int* in_sizes, int n_in,
                              void* d_out, int out_size, void* d_ws, size_t ws_size,
                              hipStream_t stream) {
    const float* x      = (const float*)d_in[0];
    const int*   ei     = (const int*)d_in[1];
    const int*   dist   = (const int*)d_in[2];
    const float* aerial = (const float*)d_in[3];
    const float* Wlin   = (const float*)d_in[4];
    const float* blin   = (const float*)d_in[5];
    const float* Wq     = (const float*)d_in[6];
    const float* bq     = (const float*)d_in[7];
    const float* Wv     = (const float*)d_in[8];
    const float* bv     = (const float*)d_in[9];
    const float* dtab   = (const float*)d_in[10];
    const float* Wl     = (const float*)d_in[11];
    const float* bl     = (const float*)d_in[12];
    const float* Wr     = (const float*)d_in[13];
    float* out = (float*)d_out;

    char* ws = (char*)d_ws;
    size_t off = 0;
    auto alloc = [&](size_t bytes) -> void* {
        void* p = ws + off;
        off += (bytes + 255) & ~(size_t)255;
        return p;
    };
    float* q32  = (float*)alloc((size_t)N_NODES * H_DIM * 4);
    float* v32  = (float*)alloc((size_t)N_NODES * H_DIM * 4);
    float* dq32 = (float*)alloc((size_t)NEMB_N * H_DIM * 4);
    unsigned long long* keys = (unsigned long long*)alloc((size_t)E_EDGES * 8);
    float* xl32 = (float*)alloc((size_t)N_NODES * H_DIM * 4);
    float* s32  = (float*)alloc((size_t)E_EDGES * 4);
    char* zbase = ws + off;
    float* msg  = (float*)alloc((size_t)N_NODES * H_DIM * 4);
    float* deg  = (float*)alloc((size_t)N_NODES * 4);
    unsigned* hist1 = (unsigned*)alloc((size_t)NB1 * 4);
    unsigned* hist2 = (unsigned*)alloc((size_t)NB2 * 4);
    unsigned long long* cand = (unsigned long long*)alloc((size_t)CAND_MAX * 8);
    unsigned* counters = (unsigned*)alloc(256);   // [0]=candCount
    SelState* st = (SelState*)alloc(256);
    size_t zlen = (size_t)((ws + off) - zbase);

    hipMemsetAsync(zbase, 0, zlen, stream);

    k_node<<<NODE_BLKS + DIST_BLKS, 128, 0, stream>>>(
        x, aerial, Wlin, blin, Wq, bq, Wv, bv, dtab, xl32, q32, v32, dq32);
    k_score<<<E_EDGES / 32, 256, 0, stream>>>(ei, dist, q32, v32, dq32,
                                              keys, s32, hist1);
    k_scan<<<1, 256, 0, stream>>>(hist1, st, 1);
    k_hist2<<<(E_EDGES + 255) / 256, 256, 0, stream>>>(s32, st, hist2);
    k_scan<<<1, 256, 0, stream>>>(hist2, st, 2);
    k_collect<<<(E_EDGES + 255) / 256, 256, 0, stream>>>(s32, keys, st, cand, &counters[0]);
    k_thresh<<<1, 256, 0, stream>>>(cand, &counters[0], st);
    k_scatter<<<E_EDGES / 4, 256, 0, stream>>>(ei, keys, st, xl32, msg, deg);
    k_out<<<N_NODES / 8, 128, 0, stream>>>(msg, deg, xl32, Wl, bl, Wr, out);
}